// Round 2
// baseline (947.680 us; speedup 1.0000x reference)
//
#include <hip/hip_runtime.h>
#include <stdint.h>

// WhiteboxGATBlock: N=100000, D=256, K=4, R=16, E=1700000 (1.6M rand + 100k self-loops)
// All tensors fp32. out = relu(H + H@M - 0.05), H = 0.5*Z + 0.5*ssa,
// M = 0.5*(Dmat - (Dmat^T Dmat) Dmat)  [eta=0.5, lam=0.1, C=0.5]

// ---------- prep: G = D^T D (256x256) ----------
__global__ void k_prep1(const float* __restrict__ D, float* __restrict__ G) {
    int i = blockIdx.x, j = threadIdx.x;
    float acc = 0.f;
    for (int d = 0; d < 256; ++d)
        acc += D[d * 256 + i] * D[d * 256 + j];
    G[i * 256 + j] = acc;
}

// ---------- prep: M = 0.5*(D - G@D) ----------
__global__ void k_prep2(const float* __restrict__ D, const float* __restrict__ G,
                        float* __restrict__ M) {
    int t = blockIdx.x, j = threadIdx.x;
    float acc = 0.f;
    for (int u = 0; u < 256; ++u)
        acc += G[t * 256 + u] * D[u * 256 + j];
    M[t * 256 + j] = 0.5f * (D[t * 256 + j] - acc);
}

// ---------- ZU[n][j] = sum_d Z[n][d]*U[k][d][r], j=k*16+r ----------
// block: 64 nodes x 64 outputs, 256 thr; thread: node t>>2, outputs (t&3)*16..+15
__global__ __launch_bounds__(256) void k_zu(const float* __restrict__ Z,
                                            const float* __restrict__ U,
                                            float* __restrict__ ZU, int n) {
    __shared__ float Us[64 * 68];   // [dd][j], pad 68
    __shared__ float Zs[64 * 65];   // [nl][dd], pad 65
    const int t = threadIdx.x;
    const int nb = blockIdx.x * 64;
    const int nc = t >> 2;
    const int c0 = (t & 3) * 16;
    const int nl_ld = t >> 2;
    const int dd_ld = (t & 3) * 16;
    const int dd_u = t >> 2;
    const int k_u = t & 3;
    float acc[16];
#pragma unroll
    for (int i = 0; i < 16; ++i) acc[i] = 0.f;

    for (int ch = 0; ch < 4; ++ch) {
        __syncthreads();
        {   // stage Z chunk [64 nodes x 64 d]
            int gn = nb + nl_ld;
            int gcl = gn < n ? gn : n - 1;
            const float4* zp = reinterpret_cast<const float4*>(
                Z + (size_t)gcl * 256 + ch * 64 + dd_ld);
            float4 z0 = zp[0], z1 = zp[1], z2 = zp[2], z3 = zp[3];
            float msk = gn < n ? 1.f : 0.f;
            float zf[16] = {z0.x, z0.y, z0.z, z0.w, z1.x, z1.y, z1.z, z1.w,
                            z2.x, z2.y, z2.z, z2.w, z3.x, z3.y, z3.z, z3.w};
#pragma unroll
            for (int i = 0; i < 16; ++i)
                Zs[nl_ld * 65 + dd_ld + i] = zf[i] * msk;
        }
        {   // stage U chunk [64 dd x 64 j]
            const float4* up = reinterpret_cast<const float4*>(
                U + k_u * 4096 + (ch * 64 + dd_u) * 16);
            float4* us = reinterpret_cast<float4*>(&Us[dd_u * 68 + k_u * 16]);
            us[0] = up[0]; us[1] = up[1]; us[2] = up[2]; us[3] = up[3];
        }
        __syncthreads();
        for (int dd = 0; dd < 64; ++dd) {
            float z = Zs[nc * 65 + dd];
            const float4* uq = reinterpret_cast<const float4*>(&Us[dd * 68 + c0]);
            float4 a = uq[0], b = uq[1], c = uq[2], d4 = uq[3];
            acc[0] += z * a.x;  acc[1] += z * a.y;  acc[2] += z * a.z;  acc[3] += z * a.w;
            acc[4] += z * b.x;  acc[5] += z * b.y;  acc[6] += z * b.z;  acc[7] += z * b.w;
            acc[8] += z * c.x;  acc[9] += z * c.y;  acc[10] += z * c.z; acc[11] += z * c.w;
            acc[12] += z * d4.x; acc[13] += z * d4.y; acc[14] += z * d4.z; acc[15] += z * d4.w;
        }
    }
    int gn = nb + nc;
    if (gn < n) {
        float4* o = reinterpret_cast<float4*>(ZU + (size_t)gn * 64 + c0);
        o[0] = make_float4(acc[0], acc[1], acc[2], acc[3]);
        o[1] = make_float4(acc[4], acc[5], acc[6], acc[7]);
        o[2] = make_float4(acc[8], acc[9], acc[10], acc[11]);
        o[3] = make_float4(acc[12], acc[13], acc[14], acc[15]);
    }
}

// ---------- edge pass: 1 wave/edge; softmax shift-invariance (self-loop => sum>=1) ----------
__global__ __launch_bounds__(256) void k_edge(const int* __restrict__ ei,
                                              const float* __restrict__ ZU,
                                              float* __restrict__ agg,
                                              float* __restrict__ segs, int E) {
    int wid = blockIdx.x * 4 + (threadIdx.x >> 6);
    int lane = threadIdx.x & 63;
    if (wid >= E) return;
    int s = ei[wid];
    int d = ei[E + wid];
    float zs = ZU[(size_t)s * 64 + lane];
    float zd = ZU[(size_t)d * 64 + lane];
    float p = zs * zd;
    p += __shfl_xor(p, 1);
    p += __shfl_xor(p, 2);
    p += __shfl_xor(p, 4);
    p += __shfl_xor(p, 8);              // per-16-lane head dot product
    float e = __expf(p * 0.25f);        // / sqrt(R)=4
    atomicAdd(&agg[(size_t)d * 64 + lane], e * zs);
    if ((lane & 15) == 0)
        atomicAdd(&segs[(size_t)d * 4 + (lane >> 4)], e);
}

// ---------- node pass: V = w_k*agg/segsum; ssa = V @ U2T; H = 0.5Z+0.5ssa (H in d_out) ----------
// block: 32 nodes, 256 thr; thread: node t>>3, 8 d per chunk at (t&7)*8
__global__ __launch_bounds__(256) void k_node(const float* __restrict__ Z,
                                              const float* __restrict__ U,
                                              const float* __restrict__ hwp,
                                              const float* __restrict__ agg,
                                              const float* __restrict__ segs,
                                              float* __restrict__ H, int n) {
    __shared__ float U2Ts[64 * 68];  // [j][dd] chunk, pad 68
    __shared__ float Vs[32 * 65];    // [nl][j], pad 65
    const int t = threadIdx.x;
    const int nb = blockIdx.x * 32;

    float h0 = hwp[0], h1 = hwp[1], h2 = hwp[2], h3 = hwp[3];
    float mx = fmaxf(fmaxf(h0, h1), fmaxf(h2, h3));
    float e0 = __expf(h0 - mx), e1 = __expf(h1 - mx),
          e2 = __expf(h2 - mx), e3 = __expf(h3 - mx);
    float es = e0 + e1 + e2 + e3;
    float wk[4] = {e0 / es, e1 / es, e2 / es, e3 / es};

    for (int idx = t; idx < 32 * 64; idx += 256) {
        int nl = idx >> 6, j = idx & 63;
        int gn = nb + nl;
        int gcl = gn < n ? gn : n - 1;
        float a = agg[(size_t)gcl * 64 + j];
        float ss = segs[(size_t)gcl * 4 + (j >> 4)];
        Vs[nl * 65 + j] = wk[j >> 4] * a / (ss + 1e-16f);
    }

    const int nl = t >> 3;
    const int dd0 = (t & 7) * 8;
    const int k_u = t & 3;
    const int dd_u = t >> 2;
    for (int ch = 0; ch < 4; ++ch) {
        __syncthreads();
        {   // stage U2T chunk [64 j x 64 dd]
            const float4* up = reinterpret_cast<const float4*>(
                U + k_u * 4096 + (ch * 64 + dd_u) * 16);
            float4 u0 = up[0], u1 = up[1], u2 = up[2], u3 = up[3];
            float uf[16] = {u0.x, u0.y, u0.z, u0.w, u1.x, u1.y, u1.z, u1.w,
                            u2.x, u2.y, u2.z, u2.w, u3.x, u3.y, u3.z, u3.w};
#pragma unroll
            for (int r = 0; r < 16; ++r)
                U2Ts[(k_u * 16 + r) * 68 + dd_u] = uf[r];
        }
        __syncthreads();
        float acc[8];
#pragma unroll
        for (int i = 0; i < 8; ++i) acc[i] = 0.f;
        for (int j = 0; j < 64; ++j) {
            float v = Vs[nl * 65 + j];
            const float4* uq = reinterpret_cast<const float4*>(&U2Ts[j * 68 + dd0]);
            float4 a = uq[0], b = uq[1];
            acc[0] += v * a.x; acc[1] += v * a.y; acc[2] += v * a.z; acc[3] += v * a.w;
            acc[4] += v * b.x; acc[5] += v * b.y; acc[6] += v * b.z; acc[7] += v * b.w;
        }
        int gn = nb + nl;
        if (gn < n) {
            const float4* zp = reinterpret_cast<const float4*>(
                Z + (size_t)gn * 256 + ch * 64 + dd0);
            float4 za = zp[0], zb = zp[1];
            float4 o0 = make_float4(0.5f * za.x + 0.5f * acc[0], 0.5f * za.y + 0.5f * acc[1],
                                    0.5f * za.z + 0.5f * acc[2], 0.5f * za.w + 0.5f * acc[3]);
            float4 o1 = make_float4(0.5f * zb.x + 0.5f * acc[4], 0.5f * zb.y + 0.5f * acc[5],
                                    0.5f * zb.z + 0.5f * acc[6], 0.5f * zb.w + 0.5f * acc[7]);
            float4* hp = reinterpret_cast<float4*>(H + (size_t)gn * 256 + ch * 64 + dd0);
            hp[0] = o0; hp[1] = o1;
        }
    }
}

// ---------- final: out = relu(H + H@M - 0.05); H lives in d_out, in-place safe ----------
// block: 64 rows, 256 thr; thread: 8 rows x (4 cols + 4 cols offset 128)
__global__ __launch_bounds__(256) void k_gemm(const float* __restrict__ H,
                                              const float* __restrict__ Mm,
                                              float* __restrict__ out, int n) {
    __shared__ float Ms[32 * 256];   // [kk][c]
    __shared__ float Hs[32 * 73];    // [kk][r], pad 73
    const int t = threadIdx.x;
    const int nb = blockIdx.x * 64;
    const int r0 = (t >> 5) * 8;
    const int c0 = (t & 31) * 4;
    const int r_ld = t >> 2;
    const int k_ld = (t & 3) * 8;
    float acc[8][8];
#pragma unroll
    for (int a = 0; a < 8; ++a)
#pragma unroll
        for (int b = 0; b < 8; ++b) acc[a][b] = 0.f;

    for (int ch = 0; ch < 8; ++ch) {
        __syncthreads();
        {   // stage H^T chunk [32 k x 64 r]
            int gn = nb + r_ld;
            int gcl = gn < n ? gn : n - 1;
            const float4* hp = reinterpret_cast<const float4*>(
                H + (size_t)gcl * 256 + ch * 32 + k_ld);
            float4 a = hp[0], b = hp[1];
            float msk = gn < n ? 1.f : 0.f;
            float f[8] = {a.x, a.y, a.z, a.w, b.x, b.y, b.z, b.w};
#pragma unroll
            for (int i = 0; i < 8; ++i)
                Hs[(k_ld + i) * 73 + r_ld] = f[i] * msk;
        }
        {   // stage M chunk [32 k x 256 c]
            const float4* mp = reinterpret_cast<const float4*>(Mm + ch * 32 * 256);
            float4* sp = reinterpret_cast<float4*>(Ms);
#pragma unroll
            for (int q = 0; q < 8; ++q)
                sp[t + q * 256] = mp[t + q * 256];
        }
        __syncthreads();
        for (int kk = 0; kk < 32; ++kk) {
            float4 m0 = *reinterpret_cast<const float4*>(&Ms[kk * 256 + c0]);
            float4 m1 = *reinterpret_cast<const float4*>(&Ms[kk * 256 + c0 + 128]);
            float h8[8];
#pragma unroll
            for (int i = 0; i < 8; ++i) h8[i] = Hs[kk * 73 + r0 + i];
#pragma unroll
            for (int a = 0; a < 8; ++a) {
                acc[a][0] += h8[a] * m0.x; acc[a][1] += h8[a] * m0.y;
                acc[a][2] += h8[a] * m0.z; acc[a][3] += h8[a] * m0.w;
                acc[a][4] += h8[a] * m1.x; acc[a][5] += h8[a] * m1.y;
                acc[a][6] += h8[a] * m1.z; acc[a][7] += h8[a] * m1.w;
            }
        }
    }
#pragma unroll
    for (int a = 0; a < 8; ++a) {
        int gn = nb + r0 + a;
        if (gn < n) {
            float4 hv0 = *reinterpret_cast<const float4*>(H + (size_t)gn * 256 + c0);
            float4 hv1 = *reinterpret_cast<const float4*>(H + (size_t)gn * 256 + c0 + 128);
            float4 o0, o1;
            o0.x = fmaxf(hv0.x + acc[a][0] - 0.05f, 0.f);
            o0.y = fmaxf(hv0.y + acc[a][1] - 0.05f, 0.f);
            o0.z = fmaxf(hv0.z + acc[a][2] - 0.05f, 0.f);
            o0.w = fmaxf(hv0.w + acc[a][3] - 0.05f, 0.f);
            o1.x = fmaxf(hv1.x + acc[a][4] - 0.05f, 0.f);
            o1.y = fmaxf(hv1.y + acc[a][5] - 0.05f, 0.f);
            o1.z = fmaxf(hv1.z + acc[a][6] - 0.05f, 0.f);
            o1.w = fmaxf(hv1.w + acc[a][7] - 0.05f, 0.f);
            *reinterpret_cast<float4*>(out + (size_t)gn * 256 + c0) = o0;
            *reinterpret_cast<float4*>(out + (size_t)gn * 256 + c0 + 128) = o1;
        }
    }
}

extern "C" void kernel_launch(void* const* d_in, const int* in_sizes, int n_in,
                              void* d_out, int out_size, void* d_ws, size_t ws_size,
                              hipStream_t stream) {
    const float* Z  = (const float*)d_in[0];
    const float* U  = (const float*)d_in[1];
    const float* Dm = (const float*)d_in[2];
    const float* hw = (const float*)d_in[3];
    const int*   ei = (const int*)d_in[4];
    const int n = in_sizes[0] / 256;       // 100000
    const int E = in_sizes[4] / 2;         // 1700000
    float* out = (float*)d_out;

    // ws layout (fp32): ZU n*64 | agg n*64 | segs n*4 | G 64K | M 64K  = ~53.3 MB
    float* ws   = (float*)d_ws;
    float* ZUb  = ws;
    float* agg  = ZUb + (size_t)n * 64;
    float* segs = agg + (size_t)n * 64;
    float* G    = segs + (size_t)n * 4;
    float* M    = G + 65536;

    hipMemsetAsync(agg, 0, (size_t)n * 68 * sizeof(float), stream);
    k_prep1<<<256, 256, 0, stream>>>(Dm, G);
    k_prep2<<<256, 256, 0, stream>>>(Dm, G, M);
    k_zu<<<(n + 63) / 64, 256, 0, stream>>>(Z, U, ZUb, n);
    k_edge<<<(E + 3) / 4, 256, 0, stream>>>(ei, ZUb, agg, segs, E);
    // H is materialized in d_out; k_gemm then reads/writes d_out in place (row-local).
    k_node<<<(n + 31) / 32, 256, 0, stream>>>(Z, U, hw, agg, segs, out, n);
    k_gemm<<<(n + 63) / 64, 256, 0, stream>>>(out, M, out, n);
}

// Round 3
// 821.369 us; speedup vs baseline: 1.1538x; 1.1538x over previous
//
#include <hip/hip_runtime.h>
#include <stdint.h>

// WhiteboxGATBlock: N=100000, D=256, K=4, R=16, E=1700000 (1.6M rand + 100k self-loops)
// All tensors fp32. out = relu(H + H@M - 0.05), H = 0.5*Z + 0.5*ssa,
// M = 0.5*(Dmat - (Dmat^T Dmat) Dmat)  [eta=0.5, lam=0.1, C=0.5]
// Edge softmax: shift-invariant, self-loop guarantees sum>=exp(|zd|^2/4)>0; fp32-safe.

// ---------- prep: G = D^T D (256x256) ----------
__global__ void k_prep1(const float* __restrict__ D, float* __restrict__ G) {
    int i = blockIdx.x, j = threadIdx.x;
    float acc = 0.f;
    for (int d = 0; d < 256; ++d)
        acc += D[d * 256 + i] * D[d * 256 + j];
    G[i * 256 + j] = acc;
}

// ---------- prep: M = 0.5*(D - G@D) ----------
__global__ void k_prep2(const float* __restrict__ D, const float* __restrict__ G,
                        float* __restrict__ M) {
    int t = blockIdx.x, j = threadIdx.x;
    float acc = 0.f;
    for (int u = 0; u < 256; ++u)
        acc += G[t * 256 + u] * D[u * 256 + j];
    M[t * 256 + j] = 0.5f * (D[t * 256 + j] - acc);
}

// ---------- ZU[n][j] = sum_d Z[n][d]*U[k][d][r], j=k*16+r ----------
__global__ __launch_bounds__(256) void k_zu(const float* __restrict__ Z,
                                            const float* __restrict__ U,
                                            float* __restrict__ ZU, int n) {
    __shared__ float Us[64 * 68];   // [dd][j], pad 68
    __shared__ float Zs[64 * 65];   // [nl][dd], pad 65
    const int t = threadIdx.x;
    const int nb = blockIdx.x * 64;
    const int nc = t >> 2;
    const int c0 = (t & 3) * 16;
    const int nl_ld = t >> 2;
    const int dd_ld = (t & 3) * 16;
    const int dd_u = t >> 2;
    const int k_u = t & 3;
    float acc[16];
#pragma unroll
    for (int i = 0; i < 16; ++i) acc[i] = 0.f;

    for (int ch = 0; ch < 4; ++ch) {
        __syncthreads();
        {   // stage Z chunk [64 nodes x 64 d]
            int gn = nb + nl_ld;
            int gcl = gn < n ? gn : n - 1;
            const float4* zp = reinterpret_cast<const float4*>(
                Z + (size_t)gcl * 256 + ch * 64 + dd_ld);
            float4 z0 = zp[0], z1 = zp[1], z2 = zp[2], z3 = zp[3];
            float msk = gn < n ? 1.f : 0.f;
            float zf[16] = {z0.x, z0.y, z0.z, z0.w, z1.x, z1.y, z1.z, z1.w,
                            z2.x, z2.y, z2.z, z2.w, z3.x, z3.y, z3.z, z3.w};
#pragma unroll
            for (int i = 0; i < 16; ++i)
                Zs[nl_ld * 65 + dd_ld + i] = zf[i] * msk;
        }
        {   // stage U chunk [64 dd x 64 j]
            const float4* up = reinterpret_cast<const float4*>(
                U + k_u * 4096 + (ch * 64 + dd_u) * 16);
            float4* us = reinterpret_cast<float4*>(&Us[dd_u * 68 + k_u * 16]);
            us[0] = up[0]; us[1] = up[1]; us[2] = up[2]; us[3] = up[3];
        }
        __syncthreads();
        for (int dd = 0; dd < 64; ++dd) {
            float z = Zs[nc * 65 + dd];
            const float4* uq = reinterpret_cast<const float4*>(&Us[dd * 68 + c0]);
            float4 a = uq[0], b = uq[1], c = uq[2], d4 = uq[3];
            acc[0] += z * a.x;  acc[1] += z * a.y;  acc[2] += z * a.z;  acc[3] += z * a.w;
            acc[4] += z * b.x;  acc[5] += z * b.y;  acc[6] += z * b.z;  acc[7] += z * b.w;
            acc[8] += z * c.x;  acc[9] += z * c.y;  acc[10] += z * c.z; acc[11] += z * c.w;
            acc[12] += z * d4.x; acc[13] += z * d4.y; acc[14] += z * d4.z; acc[15] += z * d4.w;
        }
    }
    int gn = nb + nc;
    if (gn < n) {
        float4* o = reinterpret_cast<float4*>(ZU + (size_t)gn * 64 + c0);
        o[0] = make_float4(acc[0], acc[1], acc[2], acc[3]);
        o[1] = make_float4(acc[4], acc[5], acc[6], acc[7]);
        o[2] = make_float4(acc[8], acc[9], acc[10], acc[11]);
        o[3] = make_float4(acc[12], acc[13], acc[14], acc[15]);
    }
}

// ---------- CSR build: histogram of dst ----------
__global__ __launch_bounds__(256) void k_hist(const int* __restrict__ ei,
                                              int* __restrict__ cnt, int E) {
    int e = blockIdx.x * 256 + threadIdx.x;
    if (e < E) atomicAdd(&cnt[ei[E + e]], 1);
}

// ---------- scan L1: per-block exclusive scan of cnt, emit block sums ----------
__global__ __launch_bounds__(256) void k_scan1(const int* __restrict__ cnt,
                                               int* __restrict__ off,
                                               int* __restrict__ blk, int n) {
    __shared__ int s[256];
    int t = threadIdx.x, b = blockIdx.x;
    int i = b * 256 + t;
    int v = (i < n) ? cnt[i] : 0;
    s[t] = v;
    __syncthreads();
    for (int o = 1; o < 256; o <<= 1) {
        int x = (t >= o) ? s[t - o] : 0;
        __syncthreads();
        s[t] += x;
        __syncthreads();
    }
    int incl = s[t];
    if (i < n) off[i] = incl - v;
    if (t == 255) blk[b] = incl;
}

// ---------- scan L2: single-block exclusive scan of block sums ----------
__global__ __launch_bounds__(512) void k_scan2(int* __restrict__ blk,
                                               int* __restrict__ blkoff, int nblk) {
    __shared__ int s[512];
    int t = threadIdx.x;
    int v = (t < nblk) ? blk[t] : 0;
    s[t] = v;
    __syncthreads();
    for (int o = 1; o < 512; o <<= 1) {
        int x = (t >= o) ? s[t - o] : 0;
        __syncthreads();
        s[t] += x;
        __syncthreads();
    }
    if (t < nblk) blkoff[t] = s[t] - v;
}

// ---------- scan L3: add block offsets; init cursor ----------
__global__ __launch_bounds__(256) void k_scan3(int* __restrict__ off,
                                               const int* __restrict__ blkoff,
                                               int* __restrict__ cursor, int n) {
    int i = blockIdx.x * 256 + threadIdx.x;
    if (i < n) {
        int o = off[i] + blkoff[blockIdx.x];
        off[i] = o;
        cursor[i] = o;
    }
}

// ---------- scatter src ids into dst buckets ----------
__global__ __launch_bounds__(256) void k_scatter(const int* __restrict__ ei,
                                                 int* __restrict__ cursor,
                                                 int* __restrict__ esrc, int E) {
    int e = blockIdx.x * 256 + threadIdx.x;
    if (e < E) {
        int s = ei[e];
        int d = ei[E + e];
        int idx = atomicAdd(&cursor[d], 1);
        esrc[idx] = s;
    }
}

// ---------- per-node aggregation: one wave per dst node, no fp32 atomics ----------
// V[node][j] = w_k * sum_e exp(<zs,zd>_head/4) * zs_j / sum_e exp(...)
__global__ __launch_bounds__(256) void k_agg(const float* __restrict__ ZU,
                                             const int* __restrict__ esrc,
                                             const int* __restrict__ off,
                                             const int* __restrict__ cnt,
                                             const float* __restrict__ hwp,
                                             float* __restrict__ V, int n) {
    int node = blockIdx.x * 4 + (threadIdx.x >> 6);
    int lane = threadIdx.x & 63;
    if (node >= n) return;
    float zd = ZU[(size_t)node * 64 + lane];
    int base = off[node];
    int deg = cnt[node];

    float accV = 0.f, ssum = 0.f;
    for (int c0 = 0; c0 < deg; c0 += 64) {
        int m = deg - c0;
        if (m > 64) m = 64;
        int s_l = (lane < m) ? esrc[base + c0 + lane] : 0;   // one coalesced load
        int s0 = __shfl(s_l, 0);
        float zs_next = ZU[(size_t)s0 * 64 + lane];
        for (int i = 0; i < m; ++i) {
            float zs = zs_next;
            if (i + 1 < m) {
                int s2 = __shfl(s_l, i + 1);
                zs_next = ZU[(size_t)s2 * 64 + lane];        // prefetch next row
            }
            float p = zs * zd;
            p += __shfl_xor(p, 1);
            p += __shfl_xor(p, 2);
            p += __shfl_xor(p, 4);
            p += __shfl_xor(p, 8);       // dot within 16-lane head group
            float e = __expf(p * 0.25f); // / sqrt(R)=4
            accV += e * zs;
            ssum += e;                   // uniform within head group
        }
    }
    // head softmax weight for this lane's head
    float h0 = hwp[0], h1 = hwp[1], h2 = hwp[2], h3 = hwp[3];
    float mx = fmaxf(fmaxf(h0, h1), fmaxf(h2, h3));
    float e0 = __expf(h0 - mx), e1 = __expf(h1 - mx),
          e2 = __expf(h2 - mx), e3 = __expf(h3 - mx);
    float es = e0 + e1 + e2 + e3;
    int hd = lane >> 4;
    float wk = (hd == 0 ? e0 : hd == 1 ? e1 : hd == 2 ? e2 : e3) / es;
    V[(size_t)node * 64 + lane] = wk * accV / ssum;
}

// ---------- node pass: ssa = V @ U2T; H = 0.5Z + 0.5ssa (H in d_out) ----------
__global__ __launch_bounds__(256) void k_node(const float* __restrict__ Z,
                                              const float* __restrict__ U,
                                              const float* __restrict__ Vg,
                                              float* __restrict__ H, int n) {
    __shared__ float U2Ts[64 * 68];  // [j][dd] chunk, pad 68
    __shared__ float Vs[32 * 65];    // [nl][j], pad 65
    const int t = threadIdx.x;
    const int nb = blockIdx.x * 32;

    for (int idx = t; idx < 32 * 64; idx += 256) {
        int nl = idx >> 6, j = idx & 63;
        int gn = nb + nl;
        int gcl = gn < n ? gn : n - 1;
        Vs[nl * 65 + j] = Vg[(size_t)gcl * 64 + j];
    }

    const int nl = t >> 3;
    const int dd0 = (t & 7) * 8;
    const int k_u = t & 3;
    const int dd_u = t >> 2;
    for (int ch = 0; ch < 4; ++ch) {
        __syncthreads();
        {   // stage U2T chunk [64 j x 64 dd]
            const float4* up = reinterpret_cast<const float4*>(
                U + k_u * 4096 + (ch * 64 + dd_u) * 16);
            float4 u0 = up[0], u1 = up[1], u2 = up[2], u3 = up[3];
            float uf[16] = {u0.x, u0.y, u0.z, u0.w, u1.x, u1.y, u1.z, u1.w,
                            u2.x, u2.y, u2.z, u2.w, u3.x, u3.y, u3.z, u3.w};
#pragma unroll
            for (int r = 0; r < 16; ++r)
                U2Ts[(k_u * 16 + r) * 68 + dd_u] = uf[r];
        }
        __syncthreads();
        float acc[8];
#pragma unroll
        for (int i = 0; i < 8; ++i) acc[i] = 0.f;
        for (int j = 0; j < 64; ++j) {
            float v = Vs[nl * 65 + j];
            const float4* uq = reinterpret_cast<const float4*>(&U2Ts[j * 68 + dd0]);
            float4 a = uq[0], b = uq[1];
            acc[0] += v * a.x; acc[1] += v * a.y; acc[2] += v * a.z; acc[3] += v * a.w;
            acc[4] += v * b.x; acc[5] += v * b.y; acc[6] += v * b.z; acc[7] += v * b.w;
        }
        int gn = nb + nl;
        if (gn < n) {
            const float4* zp = reinterpret_cast<const float4*>(
                Z + (size_t)gn * 256 + ch * 64 + dd0);
            float4 za = zp[0], zb = zp[1];
            float4 o0 = make_float4(0.5f * za.x + 0.5f * acc[0], 0.5f * za.y + 0.5f * acc[1],
                                    0.5f * za.z + 0.5f * acc[2], 0.5f * za.w + 0.5f * acc[3]);
            float4 o1 = make_float4(0.5f * zb.x + 0.5f * acc[4], 0.5f * zb.y + 0.5f * acc[5],
                                    0.5f * zb.z + 0.5f * acc[6], 0.5f * zb.w + 0.5f * acc[7]);
            float4* hp = reinterpret_cast<float4*>(H + (size_t)gn * 256 + ch * 64 + dd0);
            hp[0] = o0; hp[1] = o1;
        }
    }
}

// ---------- final: out = relu(H + H@M - 0.05); H lives in d_out, in-place safe ----------
__global__ __launch_bounds__(256) void k_gemm(const float* __restrict__ H,
                                              const float* __restrict__ Mm,
                                              float* __restrict__ out, int n) {
    __shared__ float Ms[32 * 256];   // [kk][c]
    __shared__ float Hs[32 * 73];    // [kk][r], pad 73
    const int t = threadIdx.x;
    const int nb = blockIdx.x * 64;
    const int r0 = (t >> 5) * 8;
    const int c0 = (t & 31) * 4;
    const int r_ld = t >> 2;
    const int k_ld = (t & 3) * 8;
    float acc[8][8];
#pragma unroll
    for (int a = 0; a < 8; ++a)
#pragma unroll
        for (int b = 0; b < 8; ++b) acc[a][b] = 0.f;

    for (int ch = 0; ch < 8; ++ch) {
        __syncthreads();
        {   // stage H^T chunk [32 k x 64 r]
            int gn = nb + r_ld;
            int gcl = gn < n ? gn : n - 1;
            const float4* hp = reinterpret_cast<const float4*>(
                H + (size_t)gcl * 256 + ch * 32 + k_ld);
            float4 a = hp[0], b = hp[1];
            float msk = gn < n ? 1.f : 0.f;
            float f[8] = {a.x, a.y, a.z, a.w, b.x, b.y, b.z, b.w};
#pragma unroll
            for (int i = 0; i < 8; ++i)
                Hs[(k_ld + i) * 73 + r_ld] = f[i] * msk;
        }
        {   // stage M chunk [32 k x 256 c]
            const float4* mp = reinterpret_cast<const float4*>(Mm + ch * 32 * 256);
            float4* sp = reinterpret_cast<float4*>(Ms);
#pragma unroll
            for (int q = 0; q < 8; ++q)
                sp[t + q * 256] = mp[t + q * 256];
        }
        __syncthreads();
        for (int kk = 0; kk < 32; ++kk) {
            float4 m0 = *reinterpret_cast<const float4*>(&Ms[kk * 256 + c0]);
            float4 m1 = *reinterpret_cast<const float4*>(&Ms[kk * 256 + c0 + 128]);
            float h8[8];
#pragma unroll
            for (int i = 0; i < 8; ++i) h8[i] = Hs[kk * 73 + r0 + i];
#pragma unroll
            for (int a = 0; a < 8; ++a) {
                acc[a][0] += h8[a] * m0.x; acc[a][1] += h8[a] * m0.y;
                acc[a][2] += h8[a] * m0.z; acc[a][3] += h8[a] * m0.w;
                acc[a][4] += h8[a] * m1.x; acc[a][5] += h8[a] * m1.y;
                acc[a][6] += h8[a] * m1.z; acc[a][7] += h8[a] * m1.w;
            }
        }
    }
#pragma unroll
    for (int a = 0; a < 8; ++a) {
        int gn = nb + r0 + a;
        if (gn < n) {
            float4 hv0 = *reinterpret_cast<const float4*>(H + (size_t)gn * 256 + c0);
            float4 hv1 = *reinterpret_cast<const float4*>(H + (size_t)gn * 256 + c0 + 128);
            float4 o0, o1;
            o0.x = fmaxf(hv0.x + acc[a][0] - 0.05f, 0.f);
            o0.y = fmaxf(hv0.y + acc[a][1] - 0.05f, 0.f);
            o0.z = fmaxf(hv0.z + acc[a][2] - 0.05f, 0.f);
            o0.w = fmaxf(hv0.w + acc[a][3] - 0.05f, 0.f);
            o1.x = fmaxf(hv1.x + acc[a][4] - 0.05f, 0.f);
            o1.y = fmaxf(hv1.y + acc[a][5] - 0.05f, 0.f);
            o1.z = fmaxf(hv1.z + acc[a][6] - 0.05f, 0.f);
            o1.w = fmaxf(hv1.w + acc[a][7] - 0.05f, 0.f);
            *reinterpret_cast<float4*>(out + (size_t)gn * 256 + c0) = o0;
            *reinterpret_cast<float4*>(out + (size_t)gn * 256 + c0 + 128) = o1;
        }
    }
}

extern "C" void kernel_launch(void* const* d_in, const int* in_sizes, int n_in,
                              void* d_out, int out_size, void* d_ws, size_t ws_size,
                              hipStream_t stream) {
    const float* Z  = (const float*)d_in[0];
    const float* U  = (const float*)d_in[1];
    const float* Dm = (const float*)d_in[2];
    const float* hw = (const float*)d_in[3];
    const int*   ei = (const int*)d_in[4];
    const int n = in_sizes[0] / 256;       // 100000
    const int E = in_sizes[4] / 2;         // 1700000
    float* out = (float*)d_out;

    // ws layout: ZU n*64 f | V n*64 f | G 64K f | M 64K f | cnt n i | off n i |
    //            cursor n i | blk 512 i | blkoff 512 i | esrc E i   (~59.8 MB)
    float* ws    = (float*)d_ws;
    float* ZUb   = ws;
    float* V     = ZUb + (size_t)n * 64;
    float* G     = V + (size_t)n * 64;
    float* M     = G + 65536;
    int* cnt     = (int*)(M + 65536);
    int* off     = cnt + n;
    int* cursor  = off + n;
    int* blk     = cursor + n;
    int* blkoff  = blk + 512;
    int* esrc    = blkoff + 512;

    const int nblk = (n + 255) / 256;      // 391 <= 512
    const int eblk = (E + 255) / 256;

    hipMemsetAsync(cnt, 0, (size_t)n * sizeof(int), stream);
    k_prep1<<<256, 256, 0, stream>>>(Dm, G);
    k_prep2<<<256, 256, 0, stream>>>(Dm, G, M);
    k_zu<<<(n + 63) / 64, 256, 0, stream>>>(Z, U, ZUb, n);
    k_hist<<<eblk, 256, 0, stream>>>(ei, cnt, E);
    k_scan1<<<nblk, 256, 0, stream>>>(cnt, off, blk, n);
    k_scan2<<<1, 512, 0, stream>>>(blk, blkoff, nblk);
    k_scan3<<<nblk, 256, 0, stream>>>(off, blkoff, cursor, n);
    k_scatter<<<eblk, 256, 0, stream>>>(ei, cursor, esrc, E);
    k_agg<<<(n + 3) / 4, 256, 0, stream>>>(ZUb, esrc, off, cnt, hw, V, n);
    // H is materialized in d_out; k_gemm then reads/writes d_out in place (row-local).
    k_node<<<(n + 31) / 32, 256, 0, stream>>>(Z, U, V, out, n);
    k_gemm<<<(n + 63) / 64, 256, 0, stream>>>(out, M, out, n);
}

// Round 4
// 676.502 us; speedup vs baseline: 1.4009x; 1.2141x over previous
//
#include <hip/hip_runtime.h>
#include <stdint.h>

// WhiteboxGATBlock: N=100000, D=256, K=4, R=16, E=1700000 (1.6M rand + 100k self-loops)
// All tensors fp32. out = relu(H @ (I + M) - 0.05), H = 0.5*Z + 0.5*ssa,
// M = 0.5*(Dmat - (Dmat^T Dmat) Dmat)  [eta=0.5, lam=0.1, C=0.5]
// Edge softmax: shift-invariant; self-loop guarantees denom >= exp(|zd|^2/4) > 0; fp32-safe.

typedef unsigned short u16;
typedef unsigned int u32;
typedef __attribute__((ext_vector_type(8))) short bf16x8;   // 4 VGPRs, MFMA A/B frag
typedef __attribute__((ext_vector_type(4))) float f32x4;    // MFMA C/D frag

__device__ __forceinline__ u16 f2bf(float f) {
    u32 u = __float_as_uint(f);
    u32 r = u + 0x7fffu + ((u >> 16) & 1u);   // RNE
    return (u16)(r >> 16);
}

// ---------- prep: G = D^T D (256x256) ----------
__global__ void k_prep1(const float* __restrict__ D, float* __restrict__ G) {
    int i = blockIdx.x, j = threadIdx.x;
    float acc = 0.f;
    for (int d = 0; d < 256; ++d)
        acc += D[d * 256 + i] * D[d * 256 + j];
    G[i * 256 + j] = acc;
}

// ---------- prep: M2t[c][k] = bf16( 0.5*(D - G@D)[k][c] + (k==c) ) ----------
__global__ void k_prep2(const float* __restrict__ D, const float* __restrict__ G,
                        u16* __restrict__ M2t) {
    int t = blockIdx.x, j = threadIdx.x;   // t = row k, j = col c
    float acc = 0.f;
    for (int u = 0; u < 256; ++u)
        acc += G[t * 256 + u] * D[u * 256 + j];
    float m = 0.5f * (D[t * 256 + j] - acc) + (t == j ? 1.f : 0.f);
    M2t[j * 256 + t] = f2bf(m);
}

// ---------- ZU[n][j] = sum_d Z[n][d]*U[k][d][r], j=k*16+r (fp32) ----------
__global__ __launch_bounds__(256) void k_zu(const float* __restrict__ Z,
                                            const float* __restrict__ U,
                                            float* __restrict__ ZU, int n) {
    __shared__ float Us[64 * 68];   // [dd][j], pad 68
    __shared__ float Zs[64 * 65];   // [nl][dd], pad 65
    const int t = threadIdx.x;
    const int nb = blockIdx.x * 64;
    const int nc = t >> 2;
    const int c0 = (t & 3) * 16;
    const int nl_ld = t >> 2;
    const int dd_ld = (t & 3) * 16;
    const int dd_u = t >> 2;
    const int k_u = t & 3;
    float acc[16];
#pragma unroll
    for (int i = 0; i < 16; ++i) acc[i] = 0.f;

    for (int ch = 0; ch < 4; ++ch) {
        __syncthreads();
        {   // stage Z chunk [64 nodes x 64 d]
            int gn = nb + nl_ld;
            int gcl = gn < n ? gn : n - 1;
            const float4* zp = reinterpret_cast<const float4*>(
                Z + (size_t)gcl * 256 + ch * 64 + dd_ld);
            float4 z0 = zp[0], z1 = zp[1], z2 = zp[2], z3 = zp[3];
            float msk = gn < n ? 1.f : 0.f;
            float zf[16] = {z0.x, z0.y, z0.z, z0.w, z1.x, z1.y, z1.z, z1.w,
                            z2.x, z2.y, z2.z, z2.w, z3.x, z3.y, z3.z, z3.w};
#pragma unroll
            for (int i = 0; i < 16; ++i)
                Zs[nl_ld * 65 + dd_ld + i] = zf[i] * msk;
        }
        {   // stage U chunk [64 dd x 64 j]
            const float4* up = reinterpret_cast<const float4*>(
                U + k_u * 4096 + (ch * 64 + dd_u) * 16);
            float4* us = reinterpret_cast<float4*>(&Us[dd_u * 68 + k_u * 16]);
            us[0] = up[0]; us[1] = up[1]; us[2] = up[2]; us[3] = up[3];
        }
        __syncthreads();
        for (int dd = 0; dd < 64; ++dd) {
            float z = Zs[nc * 65 + dd];
            const float4* uq = reinterpret_cast<const float4*>(&Us[dd * 68 + c0]);
            float4 a = uq[0], b = uq[1], c = uq[2], d4 = uq[3];
            acc[0] += z * a.x;  acc[1] += z * a.y;  acc[2] += z * a.z;  acc[3] += z * a.w;
            acc[4] += z * b.x;  acc[5] += z * b.y;  acc[6] += z * b.z;  acc[7] += z * b.w;
            acc[8] += z * c.x;  acc[9] += z * c.y;  acc[10] += z * c.z; acc[11] += z * c.w;
            acc[12] += z * d4.x; acc[13] += z * d4.y; acc[14] += z * d4.z; acc[15] += z * d4.w;
        }
    }
    int gn = nb + nc;
    if (gn < n) {
        float4* o = reinterpret_cast<float4*>(ZU + (size_t)gn * 64 + c0);
        o[0] = make_float4(acc[0], acc[1], acc[2], acc[3]);
        o[1] = make_float4(acc[4], acc[5], acc[6], acc[7]);
        o[2] = make_float4(acc[8], acc[9], acc[10], acc[11]);
        o[3] = make_float4(acc[12], acc[13], acc[14], acc[15]);
    }
}

// ---------- CSR build: histogram of dst ----------
__global__ __launch_bounds__(256) void k_hist(const int* __restrict__ ei,
                                              int* __restrict__ cnt, int E) {
    int e = blockIdx.x * 256 + threadIdx.x;
    if (e < E) atomicAdd(&cnt[ei[E + e]], 1);
}

// ---------- scan L1 ----------
__global__ __launch_bounds__(256) void k_scan1(const int* __restrict__ cnt,
                                               int* __restrict__ off,
                                               int* __restrict__ blk, int n) {
    __shared__ int s[256];
    int t = threadIdx.x, b = blockIdx.x;
    int i = b * 256 + t;
    int v = (i < n) ? cnt[i] : 0;
    s[t] = v;
    __syncthreads();
    for (int o = 1; o < 256; o <<= 1) {
        int x = (t >= o) ? s[t - o] : 0;
        __syncthreads();
        s[t] += x;
        __syncthreads();
    }
    int incl = s[t];
    if (i < n) off[i] = incl - v;
    if (t == 255) blk[b] = incl;
}

// ---------- scan L2 ----------
__global__ __launch_bounds__(512) void k_scan2(int* __restrict__ blk,
                                               int* __restrict__ blkoff, int nblk) {
    __shared__ int s[512];
    int t = threadIdx.x;
    int v = (t < nblk) ? blk[t] : 0;
    s[t] = v;
    __syncthreads();
    for (int o = 1; o < 512; o <<= 1) {
        int x = (t >= o) ? s[t - o] : 0;
        __syncthreads();
        s[t] += x;
        __syncthreads();
    }
    if (t < nblk) blkoff[t] = s[t] - v;
}

// ---------- scan L3: finalize offsets; init cursor ----------
__global__ __launch_bounds__(256) void k_scan3(int* __restrict__ off,
                                               const int* __restrict__ blkoff,
                                               int* __restrict__ cursor, int n) {
    int i = blockIdx.x * 256 + threadIdx.x;
    if (i < n) {
        int o = off[i] + blkoff[blockIdx.x];
        off[i] = o;
        cursor[i] = o;
    }
}

// ---------- scatter src ids into dst buckets ----------
__global__ __launch_bounds__(256) void k_scatter(const int* __restrict__ ei,
                                                 int* __restrict__ cursor,
                                                 int* __restrict__ esrc, int E) {
    int e = blockIdx.x * 256 + threadIdx.x;
    if (e < E) {
        int s = ei[e];
        int d = ei[E + e];
        int idx = atomicAdd(&cursor[d], 1);
        esrc[idx] = s;
    }
}

// ---------- per-node aggregation: 1 wave/node, 4 edges in flight ----------
// lane = g*16+q: group g handles edge c0+g, lane q holds dims 4q..4q+3 (float4)
__global__ __launch_bounds__(256) void k_agg(const float* __restrict__ ZU,
                                             const int* __restrict__ esrc,
                                             const int* __restrict__ off,
                                             const int* __restrict__ cnt,
                                             const float* __restrict__ hwp,
                                             float* __restrict__ V, int n) {
    int node = blockIdx.x * 4 + (threadIdx.x >> 6);
    int lane = threadIdx.x & 63;
    if (node >= n) return;
    const int q = lane & 15;
    const int g = lane >> 4;
    float4 zd4 = *reinterpret_cast<const float4*>(&ZU[(size_t)node * 64 + q * 4]);
    int base = off[node];
    int deg = cnt[node];

    float ax = 0.f, ay = 0.f, az = 0.f, aw = 0.f, ssum = 0.f;
    for (int c0 = 0; c0 < deg; c0 += 4) {
        int e = c0 + g;
        bool valid = e < deg;
        int s = valid ? esrc[base + e] : 0;
        float4 zs4 = *reinterpret_cast<const float4*>(&ZU[(size_t)s * 64 + q * 4]);
        float p = zs4.x * zd4.x + zs4.y * zd4.y + zs4.z * zd4.z + zs4.w * zd4.w;
        p += __shfl_xor(p, 1);
        p += __shfl_xor(p, 2);              // head dot across 4-lane subgroup
        float ew = valid ? __expf(p * 0.25f) : 0.f;   // / sqrt(R)=4
        ax += ew * zs4.x; ay += ew * zs4.y;
        az += ew * zs4.z; aw += ew * zs4.w;
        ssum += ew;
    }
    // reduce the 4 edge-groups
    ax += __shfl_xor(ax, 16); ax += __shfl_xor(ax, 32);
    ay += __shfl_xor(ay, 16); ay += __shfl_xor(ay, 32);
    az += __shfl_xor(az, 16); az += __shfl_xor(az, 32);
    aw += __shfl_xor(aw, 16); aw += __shfl_xor(aw, 32);
    ssum += __shfl_xor(ssum, 16); ssum += __shfl_xor(ssum, 32);

    if (g == 0) {
        float h0 = hwp[0], h1 = hwp[1], h2 = hwp[2], h3 = hwp[3];
        float mx = fmaxf(fmaxf(h0, h1), fmaxf(h2, h3));
        float e0 = __expf(h0 - mx), e1 = __expf(h1 - mx),
              e2 = __expf(h2 - mx), e3 = __expf(h3 - mx);
        float es = e0 + e1 + e2 + e3;
        int hd = q >> 2;
        float wk = (hd == 0 ? e0 : hd == 1 ? e1 : hd == 2 ? e2 : e3) / es;
        float inv = wk / ssum;
        *reinterpret_cast<float4*>(&V[(size_t)node * 64 + q * 4]) =
            make_float4(ax * inv, ay * inv, az * inv, aw * inv);
    }
}

// ---------- node pass: ssa = V @ U2T; H = 0.5Z + 0.5ssa -> bf16 Hb ----------
__global__ __launch_bounds__(256) void k_node(const float* __restrict__ Z,
                                              const float* __restrict__ U,
                                              const float* __restrict__ Vg,
                                              u16* __restrict__ Hb, int n) {
    __shared__ float U2Ts[64 * 68];  // [j][dd] chunk, pad 68
    __shared__ float Vs[32 * 65];    // [nl][j], pad 65
    const int t = threadIdx.x;
    const int nb = blockIdx.x * 32;

    for (int idx = t; idx < 32 * 64; idx += 256) {
        int nl = idx >> 6, j = idx & 63;
        int gn = nb + nl;
        int gcl = gn < n ? gn : n - 1;
        Vs[nl * 65 + j] = Vg[(size_t)gcl * 64 + j];
    }

    const int nl = t >> 3;
    const int dd0 = (t & 7) * 8;
    const int k_u = t & 3;
    const int dd_u = t >> 2;
    for (int ch = 0; ch < 4; ++ch) {
        __syncthreads();
        {   // stage U2T chunk [64 j x 64 dd]
            const float4* up = reinterpret_cast<const float4*>(
                U + k_u * 4096 + (ch * 64 + dd_u) * 16);
            float4 u0 = up[0], u1 = up[1], u2 = up[2], u3 = up[3];
            float uf[16] = {u0.x, u0.y, u0.z, u0.w, u1.x, u1.y, u1.z, u1.w,
                            u2.x, u2.y, u2.z, u2.w, u3.x, u3.y, u3.z, u3.w};
#pragma unroll
            for (int r = 0; r < 16; ++r)
                U2Ts[(k_u * 16 + r) * 68 + dd_u] = uf[r];
        }
        __syncthreads();
        float acc[8];
#pragma unroll
        for (int i = 0; i < 8; ++i) acc[i] = 0.f;
        for (int j = 0; j < 64; ++j) {
            float v = Vs[nl * 65 + j];
            const float4* uq = reinterpret_cast<const float4*>(&U2Ts[j * 68 + dd0]);
            float4 a = uq[0], b = uq[1];
            acc[0] += v * a.x; acc[1] += v * a.y; acc[2] += v * a.z; acc[3] += v * a.w;
            acc[4] += v * b.x; acc[5] += v * b.y; acc[6] += v * b.z; acc[7] += v * b.w;
        }
        int gn = nb + nl;
        if (gn < n) {
            const float4* zp = reinterpret_cast<const float4*>(
                Z + (size_t)gn * 256 + ch * 64 + dd0);
            float4 za = zp[0], zb = zp[1];
            float hv[8];
            hv[0] = 0.5f * za.x + 0.5f * acc[0]; hv[1] = 0.5f * za.y + 0.5f * acc[1];
            hv[2] = 0.5f * za.z + 0.5f * acc[2]; hv[3] = 0.5f * za.w + 0.5f * acc[3];
            hv[4] = 0.5f * zb.x + 0.5f * acc[4]; hv[5] = 0.5f * zb.y + 0.5f * acc[5];
            hv[6] = 0.5f * zb.z + 0.5f * acc[6]; hv[7] = 0.5f * zb.w + 0.5f * acc[7];
            uint4 pk;
            pk.x = (u32)f2bf(hv[0]) | ((u32)f2bf(hv[1]) << 16);
            pk.y = (u32)f2bf(hv[2]) | ((u32)f2bf(hv[3]) << 16);
            pk.z = (u32)f2bf(hv[4]) | ((u32)f2bf(hv[5]) << 16);
            pk.w = (u32)f2bf(hv[6]) | ((u32)f2bf(hv[7]) << 16);
            *reinterpret_cast<uint4*>(Hb + (size_t)gn * 256 + ch * 64 + dd0) = pk;
        }
    }
}

// ---------- final: out = relu(Hb @ M2 - 0.05) via bf16 MFMA, no LDS ----------
// block 64 rows x 256 cols, 4 waves; wave w covers cols w*64..w*64+63 (4x4 16x16 tiles)
__global__ __launch_bounds__(256) void k_gemm2(const u16* __restrict__ Hb,
                                               const u16* __restrict__ M2t,
                                               float* __restrict__ out, int n) {
    const int t = threadIdx.x;
    const int w = t >> 6;
    const int lane = t & 63;
    const int m16 = lane & 15;          // A row / D col within tile
    const int quad = lane >> 4;         // k-subblock / D row group
    const int nb = blockIdx.x * 64;

    f32x4 acc[4][4];
#pragma unroll
    for (int mt = 0; mt < 4; ++mt)
#pragma unroll
        for (int nt = 0; nt < 4; ++nt)
            acc[mt][nt] = (f32x4){0.f, 0.f, 0.f, 0.f};

    // A row pointers (clamped); rows nb+mt*16+m16
    const u16* arow[4];
#pragma unroll
    for (int mt = 0; mt < 4; ++mt) {
        int r = nb + mt * 16 + m16;
        if (r >= n) r = n - 1;
        arow[mt] = Hb + (size_t)r * 256 + quad * 8;
    }
    // B col pointers; cols w*64+nt*16+m16 (M2t is [col][k])
    const u16* bcol[4];
#pragma unroll
    for (int nt = 0; nt < 4; ++nt)
        bcol[nt] = M2t + (size_t)(w * 64 + nt * 16 + m16) * 256 + quad * 8;

    for (int ks = 0; ks < 8; ++ks) {
        bf16x8 a[4], b[4];
#pragma unroll
        for (int mt = 0; mt < 4; ++mt)
            a[mt] = *reinterpret_cast<const bf16x8*>(arow[mt] + ks * 32);
#pragma unroll
        for (int nt = 0; nt < 4; ++nt)
            b[nt] = *reinterpret_cast<const bf16x8*>(bcol[nt] + ks * 32);
#pragma unroll
        for (int mt = 0; mt < 4; ++mt)
#pragma unroll
            for (int nt = 0; nt < 4; ++nt)
                acc[mt][nt] = __builtin_amdgcn_mfma_f32_16x16x32_bf16(
                    a[mt], b[nt], acc[mt][nt], 0, 0, 0);
    }

    // epilogue: D[row=quad*4+r][col=m16] per reg r
#pragma unroll
    for (int mt = 0; mt < 4; ++mt) {
#pragma unroll
        for (int r = 0; r < 4; ++r) {
            int row = nb + mt * 16 + quad * 4 + r;
            if (row < n) {
#pragma unroll
                for (int nt = 0; nt < 4; ++nt) {
                    int col = w * 64 + nt * 16 + m16;
                    out[(size_t)row * 256 + col] =
                        fmaxf(acc[mt][nt][r] - 0.05f, 0.f);
                }
            }
        }
    }
}

extern "C" void kernel_launch(void* const* d_in, const int* in_sizes, int n_in,
                              void* d_out, int out_size, void* d_ws, size_t ws_size,
                              hipStream_t stream) {
    const float* Z  = (const float*)d_in[0];
    const float* U  = (const float*)d_in[1];
    const float* Dm = (const float*)d_in[2];
    const float* hw = (const float*)d_in[3];
    const int*   ei = (const int*)d_in[4];
    const int n = in_sizes[0] / 256;       // 100000
    const int E = in_sizes[4] / 2;         // 1700000
    float* out = (float*)d_out;

    // ws layout with lifetime aliasing (~77.2 MB):
    //   [0, n*512)            : Hb (bf16 H, live from k_node)  -- overlays:
    //       [0, n*256)        :   ZU fp32            (dead after k_agg)
    //       [n*256, +E*4)     :   esrc               (dead after k_agg)
    //       then cnt/off/cursor/blk/blkoff (ints)    (dead after k_agg)
    //   [n*512, n*512+n*256)  : V fp32
    //   then G fp32 64K, M2t bf16 64K
    char* w = (char*)d_ws;
    float* ZUb   = (float*)w;
    int* esrc    = (int*)(w + (size_t)n * 256);
    int* cnt     = esrc + E;
    int* off     = cnt + n;
    int* cursor  = off + n;
    int* blk     = cursor + n;
    int* blkoff  = blk + 512;
    u16* Hb      = (u16*)w;
    float* V     = (float*)(w + (size_t)n * 512);
    float* G     = V + (size_t)n * 64;
    u16* M2t     = (u16*)(G + 65536);

    const int nblk = (n + 255) / 256;      // 391 <= 512
    const int eblk = (E + 255) / 256;

    hipMemsetAsync(cnt, 0, (size_t)n * sizeof(int), stream);
    k_prep1<<<256, 256, 0, stream>>>(Dm, G);
    k_prep2<<<256, 256, 0, stream>>>(Dm, G, M2t);
    k_zu<<<(n + 63) / 64, 256, 0, stream>>>(Z, U, ZUb, n);
    k_hist<<<eblk, 256, 0, stream>>>(ei, cnt, E);
    k_scan1<<<nblk, 256, 0, stream>>>(cnt, off, blk, n);
    k_scan2<<<1, 512, 0, stream>>>(blk, blkoff, nblk);
    k_scan3<<<nblk, 256, 0, stream>>>(off, blkoff, cursor, n);
    k_scatter<<<eblk, 256, 0, stream>>>(ei, cursor, esrc, E);
    k_agg<<<(n + 3) / 4, 256, 0, stream>>>(ZUb, esrc, off, cnt, hw, V, n);
    k_node<<<(n + 31) / 32, 256, 0, stream>>>(Z, U, V, Hb, n);
    k_gemm2<<<(n + 63) / 64, 256, 0, stream>>>(Hb, M2t, out, n);
}

// Round 5
// 597.230 us; speedup vs baseline: 1.5868x; 1.1327x over previous
//
#include <hip/hip_runtime.h>
#include <stdint.h>

// WhiteboxGATBlock: N=100000, D=256, K=4, R=16, E=1700000 (1.6M rand + 100k self-loops)
// All tensors fp32. Algebra:
//   M = 0.5*(D - (D^T D) D), A = I + M
//   H = 0.5*Z + 0.5*V@W  (V = head-weighted normalized attention agg, W[j][d]=U[j>>4][d][j&15])
//   out = relu(H@A - 0.05) = relu( Z@(0.5A) + V@(0.5*W@A) - 0.05 )
// => single fused MFMA GEMM with K=320 over [Zb | Vb] @ [P; W2], P/W2 precomputed per call.
// Edge softmax: shift-invariant; self-loop guarantees denom > 0; fp32-safe without segmax.

typedef unsigned short u16;
typedef unsigned int u32;
typedef __attribute__((ext_vector_type(8))) short bf16x8;   // 4 VGPRs, MFMA A/B frag
typedef __attribute__((ext_vector_type(4))) float f32x4;    // MFMA C/D frag

__device__ __forceinline__ u16 f2bf(float f) {
    u32 u = __float_as_uint(f);
    u32 r = u + 0x7fffu + ((u >> 16) & 1u);   // RNE
    return (u16)(r >> 16);
}

// ---------- prep: G = D^T D (256x256) ----------
__global__ void k_prep1(const float* __restrict__ D, float* __restrict__ G) {
    int i = blockIdx.x, j = threadIdx.x;
    float acc = 0.f;
    for (int d = 0; d < 256; ++d)
        acc += D[d * 256 + i] * D[d * 256 + j];
    G[i * 256 + j] = acc;
}

// ---------- prep: A = I + 0.5*(D - G@D)  (fp32) ----------
__global__ void k_prep2(const float* __restrict__ D, const float* __restrict__ G,
                        float* __restrict__ A) {
    int t = blockIdx.x, j = threadIdx.x;   // row t, col j
    float acc = 0.f;
    for (int u = 0; u < 256; ++u)
        acc += G[t * 256 + u] * D[u * 256 + j];
    A[t * 256 + j] = 0.5f * (D[t * 256 + j] - acc) + (t == j ? 1.f : 0.f);
}

// ---------- prep: Bt[c][k] = bf16(0.5*A[k][c]) for k<256 (B stored [col][k], 320-stride) ----------
__global__ void k_prep3(const float* __restrict__ A, u16* __restrict__ Bt) {
    int c = blockIdx.x, k = threadIdx.x;
    Bt[c * 320 + k] = f2bf(0.5f * A[k * 256 + c]);
}

// ---------- prep: Bt[c][256+j] = bf16(0.5 * sum_d W[j][d]*A[d][c]),  W[j][d]=U[j>>4][d][j&15] ----------
__global__ void k_prep4(const float* __restrict__ U, const float* __restrict__ A,
                        u16* __restrict__ Bt) {
    int j = blockIdx.x, c = threadIdx.x;
    int k = j >> 4, r = j & 15;
    float acc = 0.f;
    for (int d = 0; d < 256; ++d)
        acc += U[k * 4096 + d * 16 + r] * A[d * 256 + c];
    Bt[c * 320 + 256 + j] = f2bf(0.5f * acc);
}

// ---------- ZU[n][j] = sum_d Z[n][d]*U[k][d][r] (fp32); also emit Zb = bf16(Z) ----------
__global__ __launch_bounds__(256) void k_zu(const float* __restrict__ Z,
                                            const float* __restrict__ U,
                                            float* __restrict__ ZU,
                                            u16* __restrict__ Zb, int n) {
    __shared__ float Us[64 * 68];   // [dd][j], pad 68
    __shared__ float Zs[64 * 65];   // [nl][dd], pad 65
    const int t = threadIdx.x;
    const int nb = blockIdx.x * 64;
    const int nc = t >> 2;
    const int c0 = (t & 3) * 16;
    const int nl_ld = t >> 2;
    const int dd_ld = (t & 3) * 16;
    const int dd_u = t >> 2;
    const int k_u = t & 3;
    float acc[16];
#pragma unroll
    for (int i = 0; i < 16; ++i) acc[i] = 0.f;

    for (int ch = 0; ch < 4; ++ch) {
        __syncthreads();
        {   // stage Z chunk [64 nodes x 64 d]; also write bf16 copy
            int gn = nb + nl_ld;
            int gcl = gn < n ? gn : n - 1;
            const float4* zp = reinterpret_cast<const float4*>(
                Z + (size_t)gcl * 256 + ch * 64 + dd_ld);
            float4 z0 = zp[0], z1 = zp[1], z2 = zp[2], z3 = zp[3];
            float msk = gn < n ? 1.f : 0.f;
            float zf[16] = {z0.x, z0.y, z0.z, z0.w, z1.x, z1.y, z1.z, z1.w,
                            z2.x, z2.y, z2.z, z2.w, z3.x, z3.y, z3.z, z3.w};
#pragma unroll
            for (int i = 0; i < 16; ++i)
                Zs[nl_ld * 65 + dd_ld + i] = zf[i] * msk;
            if (gn < n) {
                uint4 pk;
                pk.x = (u32)f2bf(zf[0]) | ((u32)f2bf(zf[1]) << 16)
                     | 0;  // placeholder to keep formatting simple
                pk.x = (u32)f2bf(zf[0]) | ((u32)f2bf(zf[1]) << 16);
                pk.y = (u32)f2bf(zf[2]) | ((u32)f2bf(zf[3]) << 16);
                pk.z = (u32)f2bf(zf[4]) | ((u32)f2bf(zf[5]) << 16);
                pk.w = (u32)f2bf(zf[6]) | ((u32)f2bf(zf[7]) << 16);
                uint4 pk2;
                pk2.x = (u32)f2bf(zf[8])  | ((u32)f2bf(zf[9]) << 16);
                pk2.y = (u32)f2bf(zf[10]) | ((u32)f2bf(zf[11]) << 16);
                pk2.z = (u32)f2bf(zf[12]) | ((u32)f2bf(zf[13]) << 16);
                pk2.w = (u32)f2bf(zf[14]) | ((u32)f2bf(zf[15]) << 16);
                uint4* zb = reinterpret_cast<uint4*>(
                    Zb + (size_t)gn * 256 + ch * 64 + dd_ld);
                zb[0] = pk;
                zb[1] = pk2;
            }
        }
        {   // stage U chunk [64 dd x 64 j]
            const float4* up = reinterpret_cast<const float4*>(
                U + k_u * 4096 + (ch * 64 + dd_u) * 16);
            float4* us = reinterpret_cast<float4*>(&Us[dd_u * 68 + k_u * 16]);
            us[0] = up[0]; us[1] = up[1]; us[2] = up[2]; us[3] = up[3];
        }
        __syncthreads();
        for (int dd = 0; dd < 64; ++dd) {
            float z = Zs[nc * 65 + dd];
            const float4* uq = reinterpret_cast<const float4*>(&Us[dd * 68 + c0]);
            float4 a = uq[0], b = uq[1], c = uq[2], d4 = uq[3];
            acc[0] += z * a.x;  acc[1] += z * a.y;  acc[2] += z * a.z;  acc[3] += z * a.w;
            acc[4] += z * b.x;  acc[5] += z * b.y;  acc[6] += z * b.z;  acc[7] += z * b.w;
            acc[8] += z * c.x;  acc[9] += z * c.y;  acc[10] += z * c.z; acc[11] += z * c.w;
            acc[12] += z * d4.x; acc[13] += z * d4.y; acc[14] += z * d4.z; acc[15] += z * d4.w;
        }
    }
    int gn = nb + nc;
    if (gn < n) {
        float4* o = reinterpret_cast<float4*>(ZU + (size_t)gn * 64 + c0);
        o[0] = make_float4(acc[0], acc[1], acc[2], acc[3]);
        o[1] = make_float4(acc[4], acc[5], acc[6], acc[7]);
        o[2] = make_float4(acc[8], acc[9], acc[10], acc[11]);
        o[3] = make_float4(acc[12], acc[13], acc[14], acc[15]);
    }
}

// ---------- CSR build: histogram of dst ----------
__global__ __launch_bounds__(256) void k_hist(const int* __restrict__ ei,
                                              int* __restrict__ cnt, int E) {
    int e = blockIdx.x * 256 + threadIdx.x;
    if (e < E) atomicAdd(&cnt[ei[E + e]], 1);
}

// ---------- scan L1 ----------
__global__ __launch_bounds__(256) void k_scan1(const int* __restrict__ cnt,
                                               int* __restrict__ off,
                                               int* __restrict__ blk, int n) {
    __shared__ int s[256];
    int t = threadIdx.x, b = blockIdx.x;
    int i = b * 256 + t;
    int v = (i < n) ? cnt[i] : 0;
    s[t] = v;
    __syncthreads();
    for (int o = 1; o < 256; o <<= 1) {
        int x = (t >= o) ? s[t - o] : 0;
        __syncthreads();
        s[t] += x;
        __syncthreads();
    }
    int incl = s[t];
    if (i < n) off[i] = incl - v;
    if (t == 255) blk[b] = incl;
}

// ---------- scan L2 ----------
__global__ __launch_bounds__(512) void k_scan2(int* __restrict__ blk,
                                               int* __restrict__ blkoff, int nblk) {
    __shared__ int s[512];
    int t = threadIdx.x;
    int v = (t < nblk) ? blk[t] : 0;
    s[t] = v;
    __syncthreads();
    for (int o = 1; o < 512; o <<= 1) {
        int x = (t >= o) ? s[t - o] : 0;
        __syncthreads();
        s[t] += x;
        __syncthreads();
    }
    if (t < nblk) blkoff[t] = s[t] - v;
}

// ---------- scan L3: finalize offsets; init cursor ----------
__global__ __launch_bounds__(256) void k_scan3(int* __restrict__ off,
                                               const int* __restrict__ blkoff,
                                               int* __restrict__ cursor, int n) {
    int i = blockIdx.x * 256 + threadIdx.x;
    if (i < n) {
        int o = off[i] + blkoff[blockIdx.x];
        off[i] = o;
        cursor[i] = o;
    }
}

// ---------- scatter src ids into dst buckets ----------
__global__ __launch_bounds__(256) void k_scatter(const int* __restrict__ ei,
                                                 int* __restrict__ cursor,
                                                 int* __restrict__ esrc, int E) {
    int e = blockIdx.x * 256 + threadIdx.x;
    if (e < E) {
        int s = ei[e];
        int d = ei[E + e];
        int idx = atomicAdd(&cursor[d], 1);
        esrc[idx] = s;
    }
}

// ---------- per-node aggregation: 1 wave/node, 4 edges in flight; emits bf16 V ----------
// lane = g*16+q: group g handles edge c0+g, lane q holds dims 4q..4q+3 (float4)
__global__ __launch_bounds__(256) void k_agg(const float* __restrict__ ZU,
                                             const int* __restrict__ esrc,
                                             const int* __restrict__ off,
                                             const int* __restrict__ cnt,
                                             const float* __restrict__ hwp,
                                             u16* __restrict__ Vb, int n) {
    int node = blockIdx.x * 4 + (threadIdx.x >> 6);
    int lane = threadIdx.x & 63;
    if (node >= n) return;
    const int q = lane & 15;
    const int g = lane >> 4;
    float4 zd4 = *reinterpret_cast<const float4*>(&ZU[(size_t)node * 64 + q * 4]);
    int base = off[node];
    int deg = cnt[node];

    float ax = 0.f, ay = 0.f, az = 0.f, aw = 0.f, ssum = 0.f;
    for (int c0 = 0; c0 < deg; c0 += 4) {
        int e = c0 + g;
        bool valid = e < deg;
        int s = valid ? esrc[base + e] : 0;
        float4 zs4 = *reinterpret_cast<const float4*>(&ZU[(size_t)s * 64 + q * 4]);
        float p = zs4.x * zd4.x + zs4.y * zd4.y + zs4.z * zd4.z + zs4.w * zd4.w;
        p += __shfl_xor(p, 1);
        p += __shfl_xor(p, 2);              // head dot across 4-lane subgroup
        float ew = valid ? __expf(p * 0.25f) : 0.f;   // / sqrt(R)=4
        ax += ew * zs4.x; ay += ew * zs4.y;
        az += ew * zs4.z; aw += ew * zs4.w;
        ssum += ew;
    }
    // reduce the 4 edge-groups
    ax += __shfl_xor(ax, 16); ax += __shfl_xor(ax, 32);
    ay += __shfl_xor(ay, 16); ay += __shfl_xor(ay, 32);
    az += __shfl_xor(az, 16); az += __shfl_xor(az, 32);
    aw += __shfl_xor(aw, 16); aw += __shfl_xor(aw, 32);
    ssum += __shfl_xor(ssum, 16); ssum += __shfl_xor(ssum, 32);

    if (g == 0) {
        float h0 = hwp[0], h1 = hwp[1], h2 = hwp[2], h3 = hwp[3];
        float mx = fmaxf(fmaxf(h0, h1), fmaxf(h2, h3));
        float e0 = __expf(h0 - mx), e1 = __expf(h1 - mx),
              e2 = __expf(h2 - mx), e3 = __expf(h3 - mx);
        float es = e0 + e1 + e2 + e3;
        int hd = q >> 2;
        float wk = (hd == 0 ? e0 : hd == 1 ? e1 : hd == 2 ? e2 : e3) / es;
        float inv = wk / ssum;
        uint2 pk;
        pk.x = (u32)f2bf(ax * inv) | ((u32)f2bf(ay * inv) << 16);
        pk.y = (u32)f2bf(az * inv) | ((u32)f2bf(aw * inv) << 16);
        *reinterpret_cast<uint2*>(&Vb[(size_t)node * 64 + q * 4]) = pk;
    }
}

// ---------- final fused GEMM: out = relu([Zb|Vb] @ Bt^T - 0.05), K=320, bf16 MFMA ----------
// block 64 rows x 256 cols, 4 waves; wave w covers cols w*64..w*64+63 (4x4 16x16 tiles)
__global__ __launch_bounds__(256) void k_out(const u16* __restrict__ Zb,
                                             const u16* __restrict__ Vb,
                                             const u16* __restrict__ Bt,
                                             float* __restrict__ out, int n) {
    const int t = threadIdx.x;
    const int w = t >> 6;
    const int lane = t & 63;
    const int m16 = lane & 15;          // A row / D col within tile
    const int quad = lane >> 4;         // k-subblock / D row group
    const int nb = blockIdx.x * 64;

    f32x4 acc[4][4];
#pragma unroll
    for (int mt = 0; mt < 4; ++mt)
#pragma unroll
        for (int nt = 0; nt < 4; ++nt)
            acc[mt][nt] = (f32x4){0.f, 0.f, 0.f, 0.f};

    int rowc[4];
#pragma unroll
    for (int mt = 0; mt < 4; ++mt) {
        int r = nb + mt * 16 + m16;
        rowc[mt] = r < n ? r : n - 1;
    }
    const u16* bbase[4];
#pragma unroll
    for (int nt = 0; nt < 4; ++nt)
        bbase[nt] = Bt + (size_t)(w * 64 + nt * 16 + m16) * 320 + quad * 8;

    // K-steps 0..7: A from Zb
    for (int ks = 0; ks < 8; ++ks) {
        bf16x8 a[4], b[4];
#pragma unroll
        for (int mt = 0; mt < 4; ++mt)
            a[mt] = *reinterpret_cast<const bf16x8*>(
                Zb + (size_t)rowc[mt] * 256 + ks * 32 + quad * 8);
#pragma unroll
        for (int nt = 0; nt < 4; ++nt)
            b[nt] = *reinterpret_cast<const bf16x8*>(bbase[nt] + ks * 32);
#pragma unroll
        for (int mt = 0; mt < 4; ++mt)
#pragma unroll
            for (int nt = 0; nt < 4; ++nt)
                acc[mt][nt] = __builtin_amdgcn_mfma_f32_16x16x32_bf16(
                    a[mt], b[nt], acc[mt][nt], 0, 0, 0);
    }
    // K-steps 8..9: A from Vb
#pragma unroll
    for (int ks = 8; ks < 10; ++ks) {
        bf16x8 a[4], b[4];
#pragma unroll
        for (int mt = 0; mt < 4; ++mt)
            a[mt] = *reinterpret_cast<const bf16x8*>(
                Vb + (size_t)rowc[mt] * 64 + (ks - 8) * 32 + quad * 8);
#pragma unroll
        for (int nt = 0; nt < 4; ++nt)
            b[nt] = *reinterpret_cast<const bf16x8*>(bbase[nt] + ks * 32);
#pragma unroll
        for (int mt = 0; mt < 4; ++mt)
#pragma unroll
            for (int nt = 0; nt < 4; ++nt)
                acc[mt][nt] = __builtin_amdgcn_mfma_f32_16x16x32_bf16(
                    a[mt], b[nt], acc[mt][nt], 0, 0, 0);
    }

    // epilogue: D[row=quad*4+r][col=m16]
#pragma unroll
    for (int mt = 0; mt < 4; ++mt) {
#pragma unroll
        for (int r = 0; r < 4; ++r) {
            int row = nb + mt * 16 + quad * 4 + r;
            if (row < n) {
#pragma unroll
                for (int nt = 0; nt < 4; ++nt) {
                    int col = w * 64 + nt * 16 + m16;
                    out[(size_t)row * 256 + col] =
                        fmaxf(acc[mt][nt][r] - 0.05f, 0.f);
                }
            }
        }
    }
}

extern "C" void kernel_launch(void* const* d_in, const int* in_sizes, int n_in,
                              void* d_out, int out_size, void* d_ws, size_t ws_size,
                              hipStream_t stream) {
    const float* Z  = (const float*)d_in[0];
    const float* U  = (const float*)d_in[1];
    const float* Dm = (const float*)d_in[2];
    const float* hw = (const float*)d_in[3];
    const int*   ei = (const int*)d_in[4];
    const int n = in_sizes[0] / 256;       // 100000
    const int E = in_sizes[4] / 2;         // 1700000
    float* out = (float*)d_out;

    // ws layout (~98.3 MB):
    //   ZUb  fp32 n*64   (25.6 MB)  live k_zu -> k_agg
    //   Zb   bf16 n*256  (51.2 MB)  live k_zu -> k_out
    //   Vb   bf16 n*64   (12.8 MB)  live k_agg -> k_out
    //   G,A  fp32 64K ea; Bt bf16 256*320 (160 KB)
    //   esrc int E (6.8 MB); cnt/off/cursor int n; blk/blkoff
    char* wp = (char*)d_ws;
    float* ZUb  = (float*)wp;
    u16* Zb     = (u16*)(wp + (size_t)n * 256);
    u16* Vb     = Zb + (size_t)n * 256;
    float* G    = (float*)(Vb + (size_t)n * 64);
    float* A    = G + 65536;
    u16* Bt     = (u16*)(A + 65536);
    int* esrc   = (int*)(Bt + 256 * 320);
    int* cnt    = esrc + E;
    int* off    = cnt + n;
    int* cursor = off + n;
    int* blk    = cursor + n;
    int* blkoff = blk + 512;

    const int nblk = (n + 255) / 256;      // 391 <= 512
    const int eblk = (E + 255) / 256;

    hipMemsetAsync(cnt, 0, (size_t)n * sizeof(int), stream);
    k_prep1<<<256, 256, 0, stream>>>(Dm, G);
    k_prep2<<<256, 256, 0, stream>>>(Dm, G, A);
    k_prep3<<<256, 256, 0, stream>>>(A, Bt);
    k_prep4<<<64, 256, 0, stream>>>(U, A, Bt);
    k_zu<<<(n + 63) / 64, 256, 0, stream>>>(Z, U, ZUb, Zb, n);
    k_hist<<<eblk, 256, 0, stream>>>(ei, cnt, E);
    k_scan1<<<nblk, 256, 0, stream>>>(cnt, off, blk, n);
    k_scan2<<<1, 512, 0, stream>>>(blk, blkoff, nblk);
    k_scan3<<<nblk, 256, 0, stream>>>(off, blkoff, cursor, n);
    k_scatter<<<eblk, 256, 0, stream>>>(ei, cursor, esrc, E);
    k_agg<<<(n + 3) / 4, 256, 0, stream>>>(ZUb, esrc, off, cnt, hw, Vb, n);
    k_out<<<(n + 63) / 64, 256, 0, stream>>>(Zb, Vb, Bt, out, n);
}

// Round 6
// 477.308 us; speedup vs baseline: 1.9855x; 1.2512x over previous
//
#include <hip/hip_runtime.h>
#include <stdint.h>

// WhiteboxGATBlock: N=100000, D=256, K=4, R=16, E=1700000 (1.6M rand + 100k self-loops)
// All tensors fp32. Algebra:
//   M = 0.5*(D - (D^T D) D), A = I + M
//   H = 0.5*Z + 0.5*V@W  (V = head-weighted normalized attention agg, W[j][d]=U[j>>4][d][j&15])
//   out = relu(H@A - 0.05) = relu( Z@(0.5A) + V@(0.5*W@A) - 0.05 )
// => single fused MFMA GEMM with K=320 over [Zb | Vb] @ Bt, Bt precomputed per call.
// Edge softmax: shift-invariant; self-loop guarantees denom > 0; fp32-safe without segmax.
// CSR build: deterministic two-level partition (coarse bucket = dst>>8), LDS cursors only —
// no global atomics, append-style writes for full write-combining (round-5 k_scatter wrote
// 108 MB = E*64B of partial-line evictions; this writes ~7 MB).

typedef unsigned short u16;
typedef unsigned int u32;
typedef __attribute__((ext_vector_type(8))) short bf16x8;   // 4 VGPRs, MFMA A/B frag
typedef __attribute__((ext_vector_type(4))) float f32x4;    // MFMA C/D frag

#define PB 256   // partition blocks

__device__ __forceinline__ u16 f2bf(float f) {
    u32 u = __float_as_uint(f);
    u32 r = u + 0x7fffu + ((u >> 16) & 1u);   // RNE
    return (u16)(r >> 16);
}

// ---------- prep: G = D^T D (256x256) ----------
__global__ void k_prep1(const float* __restrict__ D, float* __restrict__ G) {
    int i = blockIdx.x, j = threadIdx.x;
    float acc = 0.f;
    for (int d = 0; d < 256; ++d)
        acc += D[d * 256 + i] * D[d * 256 + j];
    G[i * 256 + j] = acc;
}

// ---------- prep: A = I + 0.5*(D - G@D)  (fp32) ----------
__global__ void k_prep2(const float* __restrict__ D, const float* __restrict__ G,
                        float* __restrict__ A) {
    int t = blockIdx.x, j = threadIdx.x;   // row t, col j
    float acc = 0.f;
    for (int u = 0; u < 256; ++u)
        acc += G[t * 256 + u] * D[u * 256 + j];
    A[t * 256 + j] = 0.5f * (D[t * 256 + j] - acc) + (t == j ? 1.f : 0.f);
}

// ---------- prep: Bt[c][k] = bf16(0.5*A[k][c]) for k<256 (B stored [col][k], 320-stride) ----------
__global__ void k_prep3(const float* __restrict__ A, u16* __restrict__ Bt) {
    int c = blockIdx.x, k = threadIdx.x;
    Bt[c * 320 + k] = f2bf(0.5f * A[k * 256 + c]);
}

// ---------- prep: Bt[c][256+j] = bf16(0.5 * sum_d W[j][d]*A[d][c]),  W[j][d]=U[j>>4][d][j&15] ----------
__global__ void k_prep4(const float* __restrict__ U, const float* __restrict__ A,
                        u16* __restrict__ Bt) {
    int j = blockIdx.x, c = threadIdx.x;
    int k = j >> 4, r = j & 15;
    float acc = 0.f;
    for (int d = 0; d < 256; ++d)
        acc += U[k * 4096 + d * 16 + r] * A[d * 256 + c];
    Bt[c * 320 + 256 + j] = f2bf(0.5f * acc);
}

// ---------- partition pass 1: per-block histogram over coarse buckets ----------
__global__ __launch_bounds__(256) void k_cnt1(const int* __restrict__ ei,
                                              int* __restrict__ cnt2, int E, int nbuck) {
    __shared__ int h[512];
    int t = threadIdx.x, b = blockIdx.x;
    for (int i = t; i < nbuck; i += 256) h[i] = 0;
    __syncthreads();
    int per = (E + PB - 1) / PB;
    int lo = b * per;
    int hi = lo + per; if (hi > E) hi = E;
    for (int e = lo + t; e < hi; e += 256)
        atomicAdd(&h[ei[E + e] >> 8], 1);
    __syncthreads();
    for (int i = t; i < nbuck; i += 256)
        cnt2[b * nbuck + i] = h[i];
}

// ---------- partition pass 2a: per-bucket scan across blocks ----------
__global__ __launch_bounds__(256) void k_cscan1(const int* __restrict__ cnt2,
                                                int* __restrict__ pre2,
                                                int* __restrict__ tot, int nbuck) {
    __shared__ int s[256];
    int t = threadIdx.x, b = blockIdx.x;
    int v = cnt2[t * nbuck + b];
    s[t] = v;
    __syncthreads();
    for (int o = 1; o < 256; o <<= 1) {
        int x = (t >= o) ? s[t - o] : 0;
        __syncthreads();
        s[t] += x;
        __syncthreads();
    }
    pre2[t * nbuck + b] = s[t] - v;
    if (t == 255) tot[b] = s[255];
}

// ---------- partition pass 2b: scan bucket totals ----------
__global__ __launch_bounds__(512) void k_cscan2(const int* __restrict__ tot,
                                                int* __restrict__ bbase, int nbuck) {
    __shared__ int s[512];
    int t = threadIdx.x;
    int v = (t < nbuck) ? tot[t] : 0;
    s[t] = v;
    __syncthreads();
    for (int o = 1; o < 512; o <<= 1) {
        int x = (t >= o) ? s[t - o] : 0;
        __syncthreads();
        s[t] += x;
        __syncthreads();
    }
    if (t < nbuck) bbase[t] = s[t] - v;
}

// ---------- partition pass 3: place packed (src<<8 | dst&255) into coarse buckets ----------
__global__ __launch_bounds__(256) void k_place(const int* __restrict__ ei,
                                               const int* __restrict__ pre2,
                                               const int* __restrict__ bbase,
                                               int* __restrict__ part, int E, int nbuck) {
    __shared__ int baseS[512];
    __shared__ int cur[512];
    int t = threadIdx.x, b = blockIdx.x;
    for (int i = t; i < nbuck; i += 256) {
        baseS[i] = bbase[i] + pre2[b * nbuck + i];
        cur[i] = 0;
    }
    __syncthreads();
    int per = (E + PB - 1) / PB;
    int lo = b * per;
    int hi = lo + per; if (hi > E) hi = E;
    for (int e = lo + t; e < hi; e += 256) {
        int s = ei[e];
        int d = ei[E + e];
        int bk = d >> 8;
        int r = atomicAdd(&cur[bk], 1);          // LDS atomic
        part[baseS[bk] + r] = (s << 8) | (d & 255);
    }
}

// ---------- partition pass 4: within-bucket CSR finalize (off/cnt/esrc), LDS cursors ----------
__global__ __launch_bounds__(256) void k_bucket(const int* __restrict__ part,
                                                const int* __restrict__ tot,
                                                const int* __restrict__ bbase,
                                                int* __restrict__ off,
                                                int* __restrict__ cnt,
                                                int* __restrict__ esrc, int n) {
    __shared__ int ncnt[256], excl[256], cur[256], sc[256];
    int t = threadIdx.x, b = blockIdx.x;
    ncnt[t] = 0;
    cur[t] = 0;
    __syncthreads();
    int base = bbase[b], m = tot[b];
    for (int i = t; i < m; i += 256)
        atomicAdd(&ncnt[part[base + i] & 255], 1);
    __syncthreads();
    int v = ncnt[t];
    sc[t] = v;
    __syncthreads();
    for (int o = 1; o < 256; o <<= 1) {
        int x = (t >= o) ? sc[t - o] : 0;
        __syncthreads();
        sc[t] += x;
        __syncthreads();
    }
    excl[t] = sc[t] - v;
    int node = b * 256 + t;
    if (node < n) {
        off[node] = base + excl[t];
        cnt[node] = v;
    }
    __syncthreads();
    for (int i = t; i < m; i += 256) {
        int pk = part[base + i];
        int j = pk & 255;
        int r = atomicAdd(&cur[j], 1);           // LDS atomic
        esrc[base + excl[j] + r] = pk >> 8;
    }
}

// ---------- ZU[n][j] = sum_d Z[n][d]*U[k][d][r] (fp32); also emit Zb = bf16(Z) ----------
__global__ __launch_bounds__(256) void k_zu(const float* __restrict__ Z,
                                            const float* __restrict__ U,
                                            float* __restrict__ ZU,
                                            u16* __restrict__ Zb, int n) {
    __shared__ float Us[64 * 68];   // [dd][j], pad 68
    __shared__ float Zs[64 * 65];   // [nl][dd], pad 65
    const int t = threadIdx.x;
    const int nb = blockIdx.x * 64;
    const int nc = t >> 2;
    const int c0 = (t & 3) * 16;
    const int nl_ld = t >> 2;
    const int dd_ld = (t & 3) * 16;
    const int dd_u = t >> 2;
    const int k_u = t & 3;
    float acc[16];
#pragma unroll
    for (int i = 0; i < 16; ++i) acc[i] = 0.f;

    for (int ch = 0; ch < 4; ++ch) {
        __syncthreads();
        {   // stage Z chunk [64 nodes x 64 d]; also write bf16 copy
            int gn = nb + nl_ld;
            int gcl = gn < n ? gn : n - 1;
            const float4* zp = reinterpret_cast<const float4*>(
                Z + (size_t)gcl * 256 + ch * 64 + dd_ld);
            float4 z0 = zp[0], z1 = zp[1], z2 = zp[2], z3 = zp[3];
            float msk = gn < n ? 1.f : 0.f;
            float zf[16] = {z0.x, z0.y, z0.z, z0.w, z1.x, z1.y, z1.z, z1.w,
                            z2.x, z2.y, z2.z, z2.w, z3.x, z3.y, z3.z, z3.w};
#pragma unroll
            for (int i = 0; i < 16; ++i)
                Zs[nl_ld * 65 + dd_ld + i] = zf[i] * msk;
            if (gn < n) {
                uint4 pk;
                pk.x = (u32)f2bf(zf[0]) | ((u32)f2bf(zf[1]) << 16);
                pk.y = (u32)f2bf(zf[2]) | ((u32)f2bf(zf[3]) << 16);
                pk.z = (u32)f2bf(zf[4]) | ((u32)f2bf(zf[5]) << 16);
                pk.w = (u32)f2bf(zf[6]) | ((u32)f2bf(zf[7]) << 16);
                uint4 pk2;
                pk2.x = (u32)f2bf(zf[8])  | ((u32)f2bf(zf[9]) << 16);
                pk2.y = (u32)f2bf(zf[10]) | ((u32)f2bf(zf[11]) << 16);
                pk2.z = (u32)f2bf(zf[12]) | ((u32)f2bf(zf[13]) << 16);
                pk2.w = (u32)f2bf(zf[14]) | ((u32)f2bf(zf[15]) << 16);
                uint4* zb = reinterpret_cast<uint4*>(
                    Zb + (size_t)gn * 256 + ch * 64 + dd_ld);
                zb[0] = pk;
                zb[1] = pk2;
            }
        }
        {   // stage U chunk [64 dd x 64 j]
            const float4* up = reinterpret_cast<const float4*>(
                U + k_u * 4096 + (ch * 64 + dd_u) * 16);
            float4* us = reinterpret_cast<float4*>(&Us[dd_u * 68 + k_u * 16]);
            us[0] = up[0]; us[1] = up[1]; us[2] = up[2]; us[3] = up[3];
        }
        __syncthreads();
        for (int dd = 0; dd < 64; ++dd) {
            float z = Zs[nc * 65 + dd];
            const float4* uq = reinterpret_cast<const float4*>(&Us[dd * 68 + c0]);
            float4 a = uq[0], b = uq[1], c = uq[2], d4 = uq[3];
            acc[0] += z * a.x;  acc[1] += z * a.y;  acc[2] += z * a.z;  acc[3] += z * a.w;
            acc[4] += z * b.x;  acc[5] += z * b.y;  acc[6] += z * b.z;  acc[7] += z * b.w;
            acc[8] += z * c.x;  acc[9] += z * c.y;  acc[10] += z * c.z; acc[11] += z * c.w;
            acc[12] += z * d4.x; acc[13] += z * d4.y; acc[14] += z * d4.z; acc[15] += z * d4.w;
        }
    }
    int gn = nb + nc;
    if (gn < n) {
        float4* o = reinterpret_cast<float4*>(ZU + (size_t)gn * 64 + c0);
        o[0] = make_float4(acc[0], acc[1], acc[2], acc[3]);
        o[1] = make_float4(acc[4], acc[5], acc[6], acc[7]);
        o[2] = make_float4(acc[8], acc[9], acc[10], acc[11]);
        o[3] = make_float4(acc[12], acc[13], acc[14], acc[15]);
    }
}

// ---------- per-node aggregation: 1 wave/node, 4 edges in flight; emits bf16 V ----------
// lane = g*16+q: group g handles edge c0+g, lane q holds dims 4q..4q+3 (float4)
__global__ __launch_bounds__(256) void k_agg(const float* __restrict__ ZU,
                                             const int* __restrict__ esrc,
                                             const int* __restrict__ off,
                                             const int* __restrict__ cnt,
                                             const float* __restrict__ hwp,
                                             u16* __restrict__ Vb, int n) {
    int node = blockIdx.x * 4 + (threadIdx.x >> 6);
    int lane = threadIdx.x & 63;
    if (node >= n) return;
    const int q = lane & 15;
    const int g = lane >> 4;
    float4 zd4 = *reinterpret_cast<const float4*>(&ZU[(size_t)node * 64 + q * 4]);
    int base = off[node];
    int deg = cnt[node];

    float ax = 0.f, ay = 0.f, az = 0.f, aw = 0.f, ssum = 0.f;
    for (int c0 = 0; c0 < deg; c0 += 4) {
        int e = c0 + g;
        bool valid = e < deg;
        int s = valid ? esrc[base + e] : 0;
        float4 zs4 = *reinterpret_cast<const float4*>(&ZU[(size_t)s * 64 + q * 4]);
        float p = zs4.x * zd4.x + zs4.y * zd4.y + zs4.z * zd4.z + zs4.w * zd4.w;
        p += __shfl_xor(p, 1);
        p += __shfl_xor(p, 2);              // head dot across 4-lane subgroup
        float ew = valid ? __expf(p * 0.25f) : 0.f;   // / sqrt(R)=4
        ax += ew * zs4.x; ay += ew * zs4.y;
        az += ew * zs4.z; aw += ew * zs4.w;
        ssum += ew;
    }
    ax += __shfl_xor(ax, 16); ax += __shfl_xor(ax, 32);
    ay += __shfl_xor(ay, 16); ay += __shfl_xor(ay, 32);
    az += __shfl_xor(az, 16); az += __shfl_xor(az, 32);
    aw += __shfl_xor(aw, 16); aw += __shfl_xor(aw, 32);
    ssum += __shfl_xor(ssum, 16); ssum += __shfl_xor(ssum, 32);

    if (g == 0) {
        float h0 = hwp[0], h1 = hwp[1], h2 = hwp[2], h3 = hwp[3];
        float mx = fmaxf(fmaxf(h0, h1), fmaxf(h2, h3));
        float e0 = __expf(h0 - mx), e1 = __expf(h1 - mx),
              e2 = __expf(h2 - mx), e3 = __expf(h3 - mx);
        float es = e0 + e1 + e2 + e3;
        int hd = q >> 2;
        float wk = (hd == 0 ? e0 : hd == 1 ? e1 : hd == 2 ? e2 : e3) / es;
        float inv = wk / ssum;
        uint2 pk;
        pk.x = (u32)f2bf(ax * inv) | ((u32)f2bf(ay * inv) << 16);
        pk.y = (u32)f2bf(az * inv) | ((u32)f2bf(aw * inv) << 16);
        *reinterpret_cast<uint2*>(&Vb[(size_t)node * 64 + q * 4]) = pk;
    }
}

// ---------- final fused GEMM: out = relu([Zb|Vb] @ Bt^T - 0.05), K=320, bf16 MFMA ----------
__global__ __launch_bounds__(256) void k_out(const u16* __restrict__ Zb,
                                             const u16* __restrict__ Vb,
                                             const u16* __restrict__ Bt,
                                             float* __restrict__ out, int n) {
    const int t = threadIdx.x;
    const int w = t >> 6;
    const int lane = t & 63;
    const int m16 = lane & 15;          // A row / D col within tile
    const int quad = lane >> 4;         // k-subblock / D row group
    const int nb = blockIdx.x * 64;

    f32x4 acc[4][4];
#pragma unroll
    for (int mt = 0; mt < 4; ++mt)
#pragma unroll
        for (int nt = 0; nt < 4; ++nt)
            acc[mt][nt] = (f32x4){0.f, 0.f, 0.f, 0.f};

    int rowc[4];
#pragma unroll
    for (int mt = 0; mt < 4; ++mt) {
        int r = nb + mt * 16 + m16;
        rowc[mt] = r < n ? r : n - 1;
    }
    const u16* bbase4[4];
#pragma unroll
    for (int nt = 0; nt < 4; ++nt)
        bbase4[nt] = Bt + (size_t)(w * 64 + nt * 16 + m16) * 320 + quad * 8;

    for (int ks = 0; ks < 8; ++ks) {
        bf16x8 a[4], b[4];
#pragma unroll
        for (int mt = 0; mt < 4; ++mt)
            a[mt] = *reinterpret_cast<const bf16x8*>(
                Zb + (size_t)rowc[mt] * 256 + ks * 32 + quad * 8);
#pragma unroll
        for (int nt = 0; nt < 4; ++nt)
            b[nt] = *reinterpret_cast<const bf16x8*>(bbase4[nt] + ks * 32);
#pragma unroll
        for (int mt = 0; mt < 4; ++mt)
#pragma unroll
            for (int nt = 0; nt < 4; ++nt)
                acc[mt][nt] = __builtin_amdgcn_mfma_f32_16x16x32_bf16(
                    a[mt], b[nt], acc[mt][nt], 0, 0, 0);
    }
#pragma unroll
    for (int ks = 8; ks < 10; ++ks) {
        bf16x8 a[4], b[4];
#pragma unroll
        for (int mt = 0; mt < 4; ++mt)
            a[mt] = *reinterpret_cast<const bf16x8*>(
                Vb + (size_t)rowc[mt] * 64 + (ks - 8) * 32 + quad * 8);
#pragma unroll
        for (int nt = 0; nt < 4; ++nt)
            b[nt] = *reinterpret_cast<const bf16x8*>(bbase4[nt] + ks * 32);
#pragma unroll
        for (int mt = 0; mt < 4; ++mt)
#pragma unroll
            for (int nt = 0; nt < 4; ++nt)
                acc[mt][nt] = __builtin_amdgcn_mfma_f32_16x16x32_bf16(
                    a[mt], b[nt], acc[mt][nt], 0, 0, 0);
    }

#pragma unroll
    for (int mt = 0; mt < 4; ++mt) {
#pragma unroll
        for (int r = 0; r < 4; ++r) {
            int row = nb + mt * 16 + quad * 4 + r;
            if (row < n) {
#pragma unroll
                for (int nt = 0; nt < 4; ++nt) {
                    int col = w * 64 + nt * 16 + m16;
                    out[(size_t)row * 256 + col] =
                        fmaxf(acc[mt][nt][r] - 0.05f, 0.f);
                }
            }
        }
    }
}

extern "C" void kernel_launch(void* const* d_in, const int* in_sizes, int n_in,
                              void* d_out, int out_size, void* d_ws, size_t ws_size,
                              hipStream_t stream) {
    const float* Z  = (const float*)d_in[0];
    const float* U  = (const float*)d_in[1];
    const float* Dm = (const float*)d_in[2];
    const float* hw = (const float*)d_in[3];
    const int*   ei = (const int*)d_in[4];
    const int n = in_sizes[0] / 256;       // 100000
    const int E = in_sizes[4] / 2;         // 1700000
    float* out = (float*)d_out;
    const int nbuck = (n + 255) >> 8;      // 391 (<= 512)

    // ws layout (~98 MB), lifetime-aliased:
    //   ZUb  fp32 n*64   (25.6 MB)  k_zu -> k_agg
    //   Zb   bf16 n*256  (51.2 MB)  k_zu -> k_out; OVERLAYS (dead after k_bucket):
    //        part int E (6.8 MB) | cnt2 int PB*nbuck | pre2 int PB*nbuck
    //   Vb   bf16 n*64   (12.8 MB)  k_agg -> k_out
    //   G, A fp32 64K ea; Bt bf16 256*320
    //   esrc int E (6.8 MB)  k_bucket -> k_agg
    //   off, cnt int n; tot, bbase int nbuck
    char* wp = (char*)d_ws;
    float* ZUb  = (float*)wp;
    u16* Zb     = (u16*)(wp + (size_t)n * 256);
    int* part   = (int*)Zb;                 // aliases Zb (dead before k_zu)
    int* cnt2   = part + E;
    int* pre2   = cnt2 + PB * nbuck;
    u16* Vb     = Zb + (size_t)n * 256;
    float* G    = (float*)(Vb + (size_t)n * 64);
    float* A    = G + 65536;
    u16* Bt     = (u16*)(A + 65536);
    int* esrc   = (int*)(Bt + 256 * 320);
    int* off    = esrc + E;
    int* cnt    = off + n;
    int* tot    = cnt + n;
    int* bbase  = tot + nbuck;

    // prep (tiny)
    k_prep1<<<256, 256, 0, stream>>>(Dm, G);
    k_prep2<<<256, 256, 0, stream>>>(Dm, G, A);
    k_prep3<<<256, 256, 0, stream>>>(A, Bt);
    k_prep4<<<64, 256, 0, stream>>>(U, A, Bt);

    // CSR build (before k_zu: part/cnt2/pre2 alias Zb)
    k_cnt1<<<PB, 256, 0, stream>>>(ei, cnt2, E, nbuck);
    k_cscan1<<<nbuck, 256, 0, stream>>>(cnt2, pre2, tot, nbuck);
    k_cscan2<<<1, 512, 0, stream>>>(tot, bbase, nbuck);
    k_place<<<PB, 256, 0, stream>>>(ei, pre2, bbase, part, E, nbuck);
    k_bucket<<<nbuck, 256, 0, stream>>>(part, tot, bbase, off, cnt, esrc, n);

    // main pipeline
    k_zu<<<(n + 63) / 64, 256, 0, stream>>>(Z, U, ZUb, Zb, n);
    k_agg<<<(n + 3) / 4, 256, 0, stream>>>(ZUb, esrc, off, cnt, hw, Vb, n);
    k_out<<<(n + 63) / 64, 256, 0, stream>>>(Zb, Vb, Bt, out, n);
}

// Round 7
// 474.295 us; speedup vs baseline: 1.9981x; 1.0064x over previous
//
#include <hip/hip_runtime.h>
#include <stdint.h>

// WhiteboxGATBlock: N=100000, D=256, K=4, R=16, E=1700000 (1.6M rand + 100k self-loops)
// All tensors fp32. Algebra:
//   M = 0.5*(D - (D^T D) D), A = I + M
//   H = 0.5*Z + 0.5*V@W  (V = head-weighted normalized attention agg, W[j][d]=U[j>>4][d][j&15])
//   out = relu(H@A - 0.05) = relu( Z@(0.5A) + V@(0.5*W@A) - 0.05 )
// => fused MFMA GEMM K=320 over [Zb | Vb] @ Bt. ZU for attention logits is ALSO an MFMA
//    GEMM now (bf16 in, fp32 acc): logit perturbation ~0.006 — inside the absmax budget.
// Edge softmax: shift-invariant; self-loop guarantees denom > 0; fp32-safe without segmax.
// CSR build: deterministic two-level partition (bucket = dst>>8), LDS cursors only.

typedef unsigned short u16;
typedef unsigned int u32;
typedef __attribute__((ext_vector_type(8))) short bf16x8;   // 4 VGPRs, MFMA A/B frag
typedef __attribute__((ext_vector_type(4))) float f32x4;    // MFMA C/D frag

#define PB 256   // partition blocks

__device__ __forceinline__ u16 f2bf(float f) {
    u32 u = __float_as_uint(f);
    u32 r = u + 0x7fffu + ((u >> 16) & 1u);   // RNE
    return (u16)(r >> 16);
}

// ---------- prep: G = D^T D (256x256) ----------
__global__ void k_prep1(const float* __restrict__ D, float* __restrict__ G) {
    int i = blockIdx.x, j = threadIdx.x;
    float acc = 0.f;
    for (int d = 0; d < 256; ++d)
        acc += D[d * 256 + i] * D[d * 256 + j];
    G[i * 256 + j] = acc;
}

// ---------- prep: A = I + 0.5*(D - G@D)  (fp32) ----------
__global__ void k_prep2(const float* __restrict__ D, const float* __restrict__ G,
                        float* __restrict__ A) {
    int t = blockIdx.x, j = threadIdx.x;   // row t, col j
    float acc = 0.f;
    for (int u = 0; u < 256; ++u)
        acc += G[t * 256 + u] * D[u * 256 + j];
    A[t * 256 + j] = 0.5f * (D[t * 256 + j] - acc) + (t == j ? 1.f : 0.f);
}

// ---------- prep: Bt[c][k] = bf16(0.5*A[k][c]) for k<256 (B stored [col][k], 320-stride) ----------
__global__ void k_prep3(const float* __restrict__ A, u16* __restrict__ Bt) {
    int c = blockIdx.x, k = threadIdx.x;
    Bt[c * 320 + k] = f2bf(0.5f * A[k * 256 + c]);
}

// ---------- prep: Bt[c][256+j] = bf16(0.5 * sum_d W[j][d]*A[d][c]) ----------
__global__ void k_prep4(const float* __restrict__ U, const float* __restrict__ A,
                        u16* __restrict__ Bt) {
    int j = blockIdx.x, c = threadIdx.x;
    int k = j >> 4, r = j & 15;
    float acc = 0.f;
    for (int d = 0; d < 256; ++d)
        acc += U[k * 4096 + d * 16 + r] * A[d * 256 + c];
    Bt[c * 320 + 256 + j] = f2bf(0.5f * acc);
}

// ---------- prep: U2t[j][d] = bf16(U[j>>4][d][j&15])  (64x256, B-operand for k_zumm) ----------
__global__ void k_prep5(const float* __restrict__ U, u16* __restrict__ U2t) {
    int j = blockIdx.x, d = threadIdx.x;
    U2t[j * 256 + d] = f2bf(U[(j >> 4) * 4096 + d * 16 + (j & 15)]);
}

// ---------- partition pass 1: per-block histogram over coarse buckets ----------
__global__ __launch_bounds__(256) void k_cnt1(const int* __restrict__ ei,
                                              int* __restrict__ cnt2, int E, int nbuck) {
    __shared__ int h[512];
    int t = threadIdx.x, b = blockIdx.x;
    for (int i = t; i < nbuck; i += 256) h[i] = 0;
    __syncthreads();
    int per = (E + PB - 1) / PB;
    int lo = b * per;
    int hi = lo + per; if (hi > E) hi = E;
    for (int e = lo + t; e < hi; e += 256)
        atomicAdd(&h[ei[E + e] >> 8], 1);
    __syncthreads();
    for (int i = t; i < nbuck; i += 256)
        cnt2[b * nbuck + i] = h[i];
}

// ---------- partition pass 2a: per-bucket scan across blocks ----------
__global__ __launch_bounds__(256) void k_cscan1(const int* __restrict__ cnt2,
                                                int* __restrict__ pre2,
                                                int* __restrict__ tot, int nbuck) {
    __shared__ int s[256];
    int t = threadIdx.x, b = blockIdx.x;
    int v = cnt2[t * nbuck + b];
    s[t] = v;
    __syncthreads();
    for (int o = 1; o < 256; o <<= 1) {
        int x = (t >= o) ? s[t - o] : 0;
        __syncthreads();
        s[t] += x;
        __syncthreads();
    }
    pre2[t * nbuck + b] = s[t] - v;
    if (t == 255) tot[b] = s[255];
}

// ---------- partition pass 2b: scan bucket totals ----------
__global__ __launch_bounds__(512) void k_cscan2(const int* __restrict__ tot,
                                                int* __restrict__ bbase, int nbuck) {
    __shared__ int s[512];
    int t = threadIdx.x;
    int v = (t < nbuck) ? tot[t] : 0;
    s[t] = v;
    __syncthreads();
    for (int o = 1; o < 512; o <<= 1) {
        int x = (t >= o) ? s[t - o] : 0;
        __syncthreads();
        s[t] += x;
        __syncthreads();
    }
    if (t < nbuck) bbase[t] = s[t] - v;
}

// ---------- partition pass 3: place packed (src<<8 | dst&255) into coarse buckets ----------
__global__ __launch_bounds__(256) void k_place(const int* __restrict__ ei,
                                               const int* __restrict__ pre2,
                                               const int* __restrict__ bbase,
                                               int* __restrict__ part, int E, int nbuck) {
    __shared__ int baseS[512];
    __shared__ int cur[512];
    int t = threadIdx.x, b = blockIdx.x;
    for (int i = t; i < nbuck; i += 256) {
        baseS[i] = bbase[i] + pre2[b * nbuck + i];
        cur[i] = 0;
    }
    __syncthreads();
    int per = (E + PB - 1) / PB;
    int lo = b * per;
    int hi = lo + per; if (hi > E) hi = E;
    for (int e = lo + t; e < hi; e += 256) {
        int s = ei[e];
        int d = ei[E + e];
        int bk = d >> 8;
        int r = atomicAdd(&cur[bk], 1);          // LDS atomic
        part[baseS[bk] + r] = (s << 8) | (d & 255);
    }
}

// ---------- partition pass 4: within-bucket CSR finalize (off/cnt/esrc), LDS cursors ----------
__global__ __launch_bounds__(256) void k_bucket(const int* __restrict__ part,
                                                const int* __restrict__ tot,
                                                const int* __restrict__ bbase,
                                                int* __restrict__ off,
                                                int* __restrict__ cnt,
                                                int* __restrict__ esrc, int n) {
    __shared__ int ncnt[256], excl[256], cur[256], sc[256];
    int t = threadIdx.x, b = blockIdx.x;
    ncnt[t] = 0;
    cur[t] = 0;
    __syncthreads();
    int base = bbase[b], m = tot[b];
    for (int i = t; i < m; i += 256)
        atomicAdd(&ncnt[part[base + i] & 255], 1);
    __syncthreads();
    int v = ncnt[t];
    sc[t] = v;
    __syncthreads();
    for (int o = 1; o < 256; o <<= 1) {
        int x = (t >= o) ? sc[t - o] : 0;
        __syncthreads();
        sc[t] += x;
        __syncthreads();
    }
    excl[t] = sc[t] - v;
    int node = b * 256 + t;
    if (node < n) {
        off[node] = base + excl[t];
        cnt[node] = v;
    }
    __syncthreads();
    for (int i = t; i < m; i += 256) {
        int pk = part[base + i];
        int j = pk & 255;
        int r = atomicAdd(&cur[j], 1);           // LDS atomic
        esrc[base + excl[j] + r] = pk >> 8;
    }
}

// ---------- cast: Zb = bf16(Z), pure streaming ----------
__global__ __launch_bounds__(256) void k_cast(const float* __restrict__ Z,
                                              u16* __restrict__ Zb, int total8) {
    int i = blockIdx.x * 256 + threadIdx.x;
    if (i >= total8) return;
    const float4* zp = reinterpret_cast<const float4*>(Z + (size_t)i * 8);
    float4 a = zp[0], b = zp[1];
    uint4 pk;
    pk.x = (u32)f2bf(a.x) | ((u32)f2bf(a.y) << 16);
    pk.y = (u32)f2bf(a.z) | ((u32)f2bf(a.w) << 16);
    pk.z = (u32)f2bf(b.x) | ((u32)f2bf(b.y) << 16);
    pk.w = (u32)f2bf(b.z) | ((u32)f2bf(b.w) << 16);
    *reinterpret_cast<uint4*>(Zb + (size_t)i * 8) = pk;
}

// ---------- ZU = Zb @ U2t^T via MFMA (fp32 out), no LDS ----------
// block = 4 waves; wave handles 16 nodes x 64 outputs; K=256 in 8 steps
__global__ __launch_bounds__(256) void k_zumm(const u16* __restrict__ Zb,
                                              const u16* __restrict__ U2t,
                                              float* __restrict__ ZU, int n) {
    const int t = threadIdx.x;
    const int w = t >> 6;
    const int lane = t & 63;
    const int m16 = lane & 15;
    const int quad = lane >> 4;
    const int nb = blockIdx.x * 64 + w * 16;

    int row = nb + m16;
    int rowc = row < n ? row : n - 1;

    f32x4 acc[4];
#pragma unroll
    for (int nt = 0; nt < 4; ++nt) acc[nt] = (f32x4){0.f, 0.f, 0.f, 0.f};

    for (int ks = 0; ks < 8; ++ks) {
        bf16x8 a = *reinterpret_cast<const bf16x8*>(
            Zb + (size_t)rowc * 256 + ks * 32 + quad * 8);
#pragma unroll
        for (int nt = 0; nt < 4; ++nt) {
            bf16x8 b = *reinterpret_cast<const bf16x8*>(
                U2t + (size_t)(nt * 16 + m16) * 256 + ks * 32 + quad * 8);
            acc[nt] = __builtin_amdgcn_mfma_f32_16x16x32_bf16(a, b, acc[nt], 0, 0, 0);
        }
    }
    // D: row=quad*4+r (node), col=m16 (output within nt tile)
#pragma unroll
    for (int r = 0; r < 4; ++r) {
        int node = nb + quad * 4 + r;
        if (node < n) {
#pragma unroll
            for (int nt = 0; nt < 4; ++nt)
                ZU[(size_t)node * 64 + nt * 16 + m16] = acc[nt][r];
        }
    }
}

// ---------- per-node aggregation: 1 wave/node, 4 edges in flight; emits bf16 V ----------
// lane = g*16+q: group g handles edge c0+g, lane q holds dims 4q..4q+3 (float4)
__global__ __launch_bounds__(256) void k_agg(const float* __restrict__ ZU,
                                             const int* __restrict__ esrc,
                                             const int* __restrict__ off,
                                             const int* __restrict__ cnt,
                                             const float* __restrict__ hwp,
                                             u16* __restrict__ Vb, int n) {
    int node = blockIdx.x * 4 + (threadIdx.x >> 6);
    int lane = threadIdx.x & 63;
    if (node >= n) return;
    const int q = lane & 15;
    const int g = lane >> 4;
    float4 zd4 = *reinterpret_cast<const float4*>(&ZU[(size_t)node * 64 + q * 4]);
    int base = off[node];
    int deg = cnt[node];

    float ax = 0.f, ay = 0.f, az = 0.f, aw = 0.f, ssum = 0.f;
    for (int c0 = 0; c0 < deg; c0 += 4) {
        int e = c0 + g;
        bool valid = e < deg;
        int s = valid ? esrc[base + e] : 0;
        float4 zs4 = *reinterpret_cast<const float4*>(&ZU[(size_t)s * 64 + q * 4]);
        float p = zs4.x * zd4.x + zs4.y * zd4.y + zs4.z * zd4.z + zs4.w * zd4.w;
        p += __shfl_xor(p, 1);
        p += __shfl_xor(p, 2);              // head dot across 4-lane subgroup
        float ew = valid ? __expf(p * 0.25f) : 0.f;   // / sqrt(R)=4
        ax += ew * zs4.x; ay += ew * zs4.y;
        az += ew * zs4.z; aw += ew * zs4.w;
        ssum += ew;
    }
    ax += __shfl_xor(ax, 16); ax += __shfl_xor(ax, 32);
    ay += __shfl_xor(ay, 16); ay += __shfl_xor(ay, 32);
    az += __shfl_xor(az, 16); az += __shfl_xor(az, 32);
    aw += __shfl_xor(aw, 16); aw += __shfl_xor(aw, 32);
    ssum += __shfl_xor(ssum, 16); ssum += __shfl_xor(ssum, 32);

    if (g == 0) {
        float h0 = hwp[0], h1 = hwp[1], h2 = hwp[2], h3 = hwp[3];
        float mx = fmaxf(fmaxf(h0, h1), fmaxf(h2, h3));
        float e0 = __expf(h0 - mx), e1 = __expf(h1 - mx),
              e2 = __expf(h2 - mx), e3 = __expf(h3 - mx);
        float es = e0 + e1 + e2 + e3;
        int hd = q >> 2;
        float wk = (hd == 0 ? e0 : hd == 1 ? e1 : hd == 2 ? e2 : e3) / es;
        float inv = wk / ssum;
        uint2 pk;
        pk.x = (u32)f2bf(ax * inv) | ((u32)f2bf(ay * inv) << 16);
        pk.y = (u32)f2bf(az * inv) | ((u32)f2bf(aw * inv) << 16);
        *reinterpret_cast<uint2*>(&Vb[(size_t)node * 64 + q * 4]) = pk;
    }
}

// ---------- final fused GEMM: out = relu([Zb|Vb] @ Bt^T - 0.05), K=320, bf16 MFMA ----------
__global__ __launch_bounds__(256) void k_out(const u16* __restrict__ Zb,
                                             const u16* __restrict__ Vb,
                                             const u16* __restrict__ Bt,
                                             float* __restrict__ out, int n) {
    const int t = threadIdx.x;
    const int w = t >> 6;
    const int lane = t & 63;
    const int m16 = lane & 15;          // A row / D col within tile
    const int quad = lane >> 4;         // k-subblock / D row group
    const int nb = blockIdx.x * 64;

    f32x4 acc[4][4];
#pragma unroll
    for (int mt = 0; mt < 4; ++mt)
#pragma unroll
        for (int nt = 0; nt < 4; ++nt)
            acc[mt][nt] = (f32x4){0.f, 0.f, 0.f, 0.f};

    int rowc[4];
#pragma unroll
    for (int mt = 0; mt < 4; ++mt) {
        int r = nb + mt * 16 + m16;
        rowc[mt] = r < n ? r : n - 1;
    }
    const u16* bbase4[4];
#pragma unroll
    for (int nt = 0; nt < 4; ++nt)
        bbase4[nt] = Bt + (size_t)(w * 64 + nt * 16 + m16) * 320 + quad * 8;

    for (int ks = 0; ks < 8; ++ks) {
        bf16x8 a[4], b[4];
#pragma unroll
        for (int mt = 0; mt < 4; ++mt)
            a[mt] = *reinterpret_cast<const bf16x8*>(
                Zb + (size_t)rowc[mt] * 256 + ks * 32 + quad * 8);
#pragma unroll
        for (int nt = 0; nt < 4; ++nt)
            b[nt] = *reinterpret_cast<const bf16x8*>(bbase4[nt] + ks * 32);
#pragma unroll
        for (int mt = 0; mt < 4; ++mt)
#pragma unroll
            for (int nt = 0; nt < 4; ++nt)
                acc[mt][nt] = __builtin_amdgcn_mfma_f32_16x16x32_bf16(
                    a[mt], b[nt], acc[mt][nt], 0, 0, 0);
    }
#pragma unroll
    for (int ks = 8; ks < 10; ++ks) {
        bf16x8 a[4], b[4];
#pragma unroll
        for (int mt = 0; mt < 4; ++mt)
            a[mt] = *reinterpret_cast<const bf16x8*>(
                Vb + (size_t)rowc[mt] * 64 + (ks - 8) * 32 + quad * 8);
#pragma unroll
        for (int nt = 0; nt < 4; ++nt)
            b[nt] = *reinterpret_cast<const bf16x8*>(bbase4[nt] + ks * 32);
#pragma unroll
        for (int mt = 0; mt < 4; ++mt)
#pragma unroll
            for (int nt = 0; nt < 4; ++nt)
                acc[mt][nt] = __builtin_amdgcn_mfma_f32_16x16x32_bf16(
                    a[mt], b[nt], acc[mt][nt], 0, 0, 0);
    }

#pragma unroll
    for (int mt = 0; mt < 4; ++mt) {
#pragma unroll
        for (int r = 0; r < 4; ++r) {
            int row = nb + mt * 16 + quad * 4 + r;
            if (row < n) {
#pragma unroll
                for (int nt = 0; nt < 4; ++nt) {
                    int col = w * 64 + nt * 16 + m16;
                    out[(size_t)row * 256 + col] =
                        fmaxf(acc[mt][nt][r] - 0.05f, 0.f);
                }
            }
        }
    }
}

extern "C" void kernel_launch(void* const* d_in, const int* in_sizes, int n_in,
                              void* d_out, int out_size, void* d_ws, size_t ws_size,
                              hipStream_t stream) {
    const float* Z  = (const float*)d_in[0];
    const float* U  = (const float*)d_in[1];
    const float* Dm = (const float*)d_in[2];
    const float* hw = (const float*)d_in[3];
    const int*   ei = (const int*)d_in[4];
    const int n = in_sizes[0] / 256;       // 100000
    const int E = in_sizes[4] / 2;         // 1700000
    float* out = (float*)d_out;
    const int nbuck = (n + 255) >> 8;      // 391 (<= 512)

    // ws layout (~98 MB), lifetime-aliased:
    //   ZUb  fp32 n*64   (25.6 MB)  k_zumm -> k_agg
    //   Zb   bf16 n*256  (51.2 MB)  k_cast -> k_out; OVERLAYS (dead after k_bucket):
    //        part int E (6.8 MB) | cnt2 int PB*nbuck | pre2 int PB*nbuck
    //   Vb   bf16 n*64   (12.8 MB)  k_agg -> k_out
    //   G, A fp32 64K ea; Bt bf16 256*320; U2t bf16 64*256
    //   esrc int E (6.8 MB)  k_bucket -> k_agg
    //   off, cnt int n; tot, bbase int nbuck
    char* wp = (char*)d_ws;
    float* ZUb  = (float*)wp;
    u16* Zb     = (u16*)(wp + (size_t)n * 256);
    int* part   = (int*)Zb;                 // aliases Zb (dead before k_cast)
    int* cnt2   = part + E;
    int* pre2   = cnt2 + PB * nbuck;
    u16* Vb     = Zb + (size_t)n * 256;
    float* G    = (float*)(Vb + (size_t)n * 64);
    float* A    = G + 65536;
    u16* Bt     = (u16*)(A + 65536);
    u16* U2t    = Bt + 256 * 320;
    int* esrc   = (int*)(U2t + 64 * 256);
    int* off    = esrc + E;
    int* cnt    = off + n;
    int* tot    = cnt + n;
    int* bbase  = tot + nbuck;

    // prep (tiny)
    k_prep1<<<256, 256, 0, stream>>>(Dm, G);
    k_prep2<<<256, 256, 0, stream>>>(Dm, G, A);
    k_prep3<<<256, 256, 0, stream>>>(A, Bt);
    k_prep4<<<64, 256, 0, stream>>>(U, A, Bt);
    k_prep5<<<64, 256, 0, stream>>>(U, U2t);

    // CSR build (before k_cast: part/cnt2/pre2 alias Zb)
    k_cnt1<<<PB, 256, 0, stream>>>(ei, cnt2, E, nbuck);
    k_cscan1<<<nbuck, 256, 0, stream>>>(cnt2, pre2, tot, nbuck);
    k_cscan2<<<1, 512, 0, stream>>>(tot, bbase, nbuck);
    k_place<<<PB, 256, 0, stream>>>(ei, pre2, bbase, part, E, nbuck);
    k_bucket<<<nbuck, 256, 0, stream>>>(part, tot, bbase, off, cnt, esrc, n);

    // main pipeline
    k_cast<<<(n * 256 / 8 + 255) / 256, 256, 0, stream>>>(Z, Zb, n * 32);
    k_zumm<<<(n + 63) / 64, 256, 0, stream>>>(Zb, U2t, ZUb, n);
    k_agg<<<(n + 3) / 4, 256, 0, stream>>>(ZUb, esrc, off, cnt, hw, Vb, n);
    k_out<<<(n + 63) / 64, 256, 0, stream>>>(Zb, Vb, Bt, out, n);
}